// Round 8
// baseline (1270.023 us; speedup 1.0000x reference)
//
#include <hip/hip_runtime.h>

#define N_NODES 100000
#define N_EDGES 1600000
#define F_IN    32
#define HD      64
#define EPS     1e-5f
#define SCAN_B  512
#define SCAN_G  ((N_NODES + SCAN_B - 1) / SCAN_B)   // 196
#define GROWS   16

// ---------------- edge-index dtype probe ----------------
__global__ void k_detect(const int* __restrict__ ei, int* __restrict__ flag) {
    if (threadIdx.x == 0 && blockIdx.x == 0) {
        int all_zero = 1;
        for (int k = 0; k < 64; ++k)
            if (ei[2 * k + 1] != 0) { all_zero = 0; break; }
        *flag = all_zero;   // 1 -> int64 layout, 0 -> int32 layout
    }
}

__device__ __forceinline__ int load_src(const int* ei, int e, int is64) {
    return is64 ? ei[2 * e] : ei[e];
}
__device__ __forceinline__ int load_dst(const int* ei, int e, int is64) {
    return is64 ? ei[2 * (N_EDGES + e)] : ei[N_EDGES + e];
}

// ---------------- degree histogram ----------------
__global__ void k_deg(const int* __restrict__ ei, const int* __restrict__ flag,
                      int* __restrict__ deg) {
    int e = blockIdx.x * blockDim.x + threadIdx.x;
    if (e >= N_EDGES) return;
    int is64 = *flag;
    atomicAdd(&deg[load_dst(ei, e, is64)], 1);
}

__global__ void k_dinv(const int* __restrict__ deg, float* __restrict__ dinv) {
    int n = blockIdx.x * blockDim.x + threadIdx.x;
    if (n >= N_NODES) return;
    dinv[n] = rsqrtf((float)deg[n] + 1.0f);
}

// ---------------- hierarchical scan ----------------
__global__ void k_scan1(const int* __restrict__ deg, int* __restrict__ bsum) {
    int t = threadIdx.x;
    int i = blockIdx.x * SCAN_B + t;
    __shared__ int ls[SCAN_B];
    ls[t] = (i < N_NODES) ? deg[i] : 0;
    __syncthreads();
    for (int off = SCAN_B / 2; off > 0; off >>= 1) {
        if (t < off) ls[t] += ls[t + off];
        __syncthreads();
    }
    if (t == 0) bsum[blockIdx.x] = ls[0];
}

__global__ void k_scan2(const int* __restrict__ bsum, int* __restrict__ boff,
                        int* __restrict__ row_start_last) {
    __shared__ int ls[256];
    int t = threadIdx.x;
    ls[t] = (t < SCAN_G) ? bsum[t] : 0;
    __syncthreads();
    for (int off = 1; off < 256; off <<= 1) {
        int u = (t >= off) ? ls[t - off] : 0;
        __syncthreads();
        ls[t] += u;
        __syncthreads();
    }
    boff[t] = (t == 0) ? 0 : ls[t - 1];
    if (t == 255) *row_start_last = ls[255];
}

// reads deg, writes row_start and cursor (cursor aliases deg: per-index read-before-write)
__global__ void k_scan3(const int* __restrict__ deg, const int* __restrict__ boff,
                        int* __restrict__ row_start, int* __restrict__ cursor) {
    int t = threadIdx.x;
    int i = blockIdx.x * SCAN_B + t;
    int v = (i < N_NODES) ? deg[i] : 0;
    __shared__ int ls[SCAN_B];
    ls[t] = v;
    __syncthreads();
    for (int off = 1; off < SCAN_B; off <<= 1) {
        int u = (t >= off) ? ls[t - off] : 0;
        __syncthreads();
        ls[t] += u;
        __syncthreads();
    }
    if (i < N_NODES) {
        int ex = boff[blockIdx.x] + ls[t] - v;
        row_start[i] = ex;
        cursor[i] = ex;
    }
}

// ---------------- bucket edges into CSR ----------------
__global__ void k_bucket(const int* __restrict__ ei, const int* __restrict__ flag,
                         int* __restrict__ cursor, int* __restrict__ csr_src) {
    int e = blockIdx.x * blockDim.x + threadIdx.x;
    if (e >= N_EDGES) return;
    int is64 = *flag;
    int s = load_src(ei, e, is64);
    int d = load_dst(ei, e, is64);
    int pos = atomicAdd(&cursor[d], 1);
    csr_src[pos] = s;
}

// ---------------- node embedding: h = x @ W_embed + b ----------------
__global__ void k_embed(const float* __restrict__ x, const float* __restrict__ W,
                        const float* __restrict__ b, float* __restrict__ h) {
    __shared__ float Ws[F_IN * HD];
    __shared__ float xs[4 * F_IN];
    int t = threadIdx.x;
    for (int i = t; i < F_IN * HD; i += 256) Ws[i] = W[i];
    if (t < 4 * F_IN) {
        int r = t >> 5, c = t & 31;
        int node = blockIdx.x * 4 + r;
        xs[t] = (node < N_NODES) ? x[node * F_IN + c] : 0.f;
    }
    __syncthreads();
    int r = t >> 6, j = t & 63;
    int node = blockIdx.x * 4 + r;
    float acc = b[j];
#pragma unroll
    for (int k = 0; k < F_IN; ++k)
        acc = fmaf(xs[r * F_IN + k], Ws[k * HD + j], acc);
    if (node < N_NODES) h[node * HD + j] = acc;
}

// ---------------- GEMM: C[n] = (relu(a*A[n]+c) @ W) * dinv[n] ----------------
// coef == nullptr -> no affine (layer 0). 16 rows/block, 4 outputs/thread.
__global__ void __launch_bounds__(256)
k_gemm64(const float* __restrict__ A, const float* __restrict__ W,
         const float* __restrict__ coef, const float* __restrict__ dinv,
         float* __restrict__ C) {
    __shared__ float Ws[HD * HD];     // 16 KB
    __shared__ float As[GROWS * HD];  // 4 KB
    int t = threadIdx.x;
    int base = blockIdx.x * GROWS;
    for (int i = t; i < HD * HD; i += 256) Ws[i] = W[i];
    for (int i = t; i < GROWS * HD; i += 256) {
        int r = i >> 6, c = i & 63;
        int node = base + r;
        float v = (node < N_NODES) ? A[node * HD + c] : 0.f;
        if (coef) v = fmaxf(fmaf(coef[c], v, coef[64 + c]), 0.f);
        As[i] = v;
    }
    __syncthreads();
    int r = t >> 6, j = t & 63;
    float acc0 = 0.f, acc1 = 0.f, acc2 = 0.f, acc3 = 0.f;
#pragma unroll
    for (int k = 0; k < HD; ++k) {
        float w = Ws[k * HD + j];
        acc0 = fmaf(As[(r     ) * HD + k], w, acc0);
        acc1 = fmaf(As[(r +  4) * HD + k], w, acc1);
        acc2 = fmaf(As[(r +  8) * HD + k], w, acc2);
        acc3 = fmaf(As[(r + 12) * HD + k], w, acc3);
    }
    int n0 = base + r;
    if (n0      < N_NODES) C[(n0     ) * HD + j] = acc0 * dinv[n0];
    if (n0 + 4  < N_NODES) C[(n0 +  4) * HD + j] = acc1 * dinv[n0 + 4];
    if (n0 + 8  < N_NODES) C[(n0 +  8) * HD + j] = acc2 * dinv[n0 + 8];
    if (n0 + 12 < N_NODES) C[(n0 + 12) * HD + j] = acc3 * dinv[n0 + 12];
}

// ---------------- CSR gather-aggregate ----------------
// xw is pre-scaled by dinv[src]; h[n] = dinv[n]*(xw[n] + sum_e xw[src_e]) + cb
__global__ void __launch_bounds__(256)
k_gather(const float* __restrict__ xw, const int* __restrict__ row_start,
         const int* __restrict__ csr_src, const float* __restrict__ dinv,
         const float* __restrict__ cb, float* __restrict__ h) {
    int wid = threadIdx.x >> 6;
    int lane = threadIdx.x & 63;
    int n = blockIdx.x * 4 + wid;
    if (n >= N_NODES) return;
    int beg = row_start[n], end = row_start[n + 1];
    float acc = xw[n * HD + lane];
    for (int base = beg; base < end; base += 64) {
        int cnt = min(64, end - base);
        int s = 0;
        if (lane < cnt) s = csr_src[base + lane];
        for (int k = 0; k < cnt; ++k) {
            int sk = __shfl(s, k);
            acc += xw[sk * HD + lane];
        }
    }
    h[n * HD + lane] = fmaf(acc, dinv[n], cb[lane]);
}

// ---------------- BN stats: per-column sum & sumsq ----------------
__global__ void k_bn_stats(const float* __restrict__ h, float* __restrict__ stats) {
    int t = threadIdx.x;
    int j = t & 63, rg = t >> 6;
    float s = 0.f, s2 = 0.f;
    for (int n = blockIdx.x * 4 + rg; n < N_NODES; n += gridDim.x * 4) {
        float v = h[n * HD + j];
        s += v;
        s2 = fmaf(v, v, s2);
    }
    __shared__ float ls[256], ls2[256];
    ls[t] = s; ls2[t] = s2;
    __syncthreads();
    if (t < 64) {
        s  = ls[t] + ls[t + 64] + ls[t + 128] + ls[t + 192];
        s2 = ls2[t] + ls2[t + 64] + ls2[t + 128] + ls2[t + 192];
        atomicAdd(&stats[j], s);
        atomicAdd(&stats[64 + j], s2);
    }
}

// ---------------- stats -> affine coef (a, c): bn(v) = a*v + c ----------------
__global__ void k_bn_coef(const float* __restrict__ stats, const float* __restrict__ gamma,
                          const float* __restrict__ beta, float* __restrict__ coef) {
    int j = threadIdx.x;   // 64
    float mu  = stats[j] * (1.0f / N_NODES);
    float var = stats[64 + j] * (1.0f / N_NODES) - mu * mu;
    float rs  = rsqrtf(var + EPS);
    float a   = gamma[j] * rs;
    coef[j]      = a;
    coef[64 + j] = fmaf(-a, mu, beta[j]);
}

// ---------------- mean pool with fused BN+ReLU ----------------
__global__ void k_pool(const float* __restrict__ h, const float* __restrict__ coef,
                       float* __restrict__ pooled) {
    int t = threadIdx.x;
    int j = t & 63, rg = t >> 6;
    float a = coef[j], c = coef[64 + j];
    float s = 0.f;
    for (int n = blockIdx.x * 4 + rg; n < N_NODES; n += gridDim.x * 4)
        s += fmaxf(fmaf(a, h[n * HD + j], c), 0.f);
    __shared__ float ls[256];
    ls[t] = s;
    __syncthreads();
    if (t < 64)
        atomicAdd(&pooled[j], ls[t] + ls[t + 64] + ls[t + 128] + ls[t + 192]);
}

// ---------------- output ----------------
__global__ void k_out(const float* __restrict__ pooled, const float* __restrict__ Wout,
                      const float* __restrict__ bout, float* __restrict__ out) {
    int o = threadIdx.x;
    float acc = bout[o];
#pragma unroll
    for (int k = 0; k < HD; ++k)
        acc = fmaf(pooled[k] * (1.0f / N_NODES), Wout[k * HD + o], acc);
    out[o] = acc;
}

extern "C" void kernel_launch(void* const* d_in, const int* in_sizes, int n_in,
                              void* d_out, int out_size, void* d_ws, size_t ws_size,
                              hipStream_t stream) {
    const float* x        = (const float*)d_in[0];
    const int*   ei       = (const int*)  d_in[1];
    const float* W_embed  = (const float*)d_in[2];
    const float* b_embed  = (const float*)d_in[3];
    const float* conv_W   = (const float*)d_in[4];
    const float* conv_b   = (const float*)d_in[5];
    const float* bn_gamma = (const float*)d_in[6];
    const float* bn_beta  = (const float*)d_in[7];
    const float* W_out    = (const float*)d_in[8];
    const float* b_out    = (const float*)d_in[9];
    float* out = (float*)d_out;

    float* ws = (float*)d_ws;
    int*   deg       = (int*)ws;                          // N (becomes cursor after scan3)
    float* dinv      = ws + N_NODES;                      // N
    int*   row_start = (int*)(ws + 2 * N_NODES);          // N+1 (pad 8)
    float* small     = ws + 3 * N_NODES + 8;
    int*   bsum      = (int*)small;                       // 256
    int*   boff      = (int*)(small + 256);               // 256
    float* stats     = small + 512;                       // 128
    float* pooled    = small + 640;                       // 64
    float* coef      = small + 704;                       // 4*128 = 512
    int*   flag      = (int*)(small + 1216);              // 1 (pad 64)
    int*   csr_src   = (int*)(small + 1280);              // E
    float* bufA      = small + 1280 + N_EDGES;            // N*64
    float* bufB      = bufA + N_NODES * HD;               // N*64

    hipMemsetAsync(deg, 0, N_NODES * sizeof(int), stream);
    k_detect<<<1, 64, 0, stream>>>(ei, flag);
    k_deg<<<(N_EDGES + 255) / 256, 256, 0, stream>>>(ei, flag, deg);
    k_dinv<<<(N_NODES + 255) / 256, 256, 0, stream>>>(deg, dinv);
    k_scan1<<<SCAN_G, SCAN_B, 0, stream>>>(deg, bsum);
    k_scan2<<<1, 256, 0, stream>>>(bsum, boff, ((int*)(ws + 2 * N_NODES)) + N_NODES);
    k_scan3<<<SCAN_G, SCAN_B, 0, stream>>>(deg, boff, row_start, deg /*cursor aliases deg*/);
    k_embed<<<(N_NODES + 3) / 4, 256, 0, stream>>>(x, W_embed, b_embed, bufA);
    k_bucket<<<(N_EDGES + 255) / 256, 256, 0, stream>>>(ei, flag, deg, csr_src);

    for (int l = 0; l < 4; ++l) {
        k_gemm64<<<(N_NODES + GROWS - 1) / GROWS, 256, 0, stream>>>(
            bufA, conv_W + l * HD * HD, l ? coef + (l - 1) * 128 : nullptr, dinv, bufB);
        k_gather<<<(N_NODES + 3) / 4, 256, 0, stream>>>(bufB, row_start, csr_src, dinv,
                                                        conv_b + l * HD, bufA);
        hipMemsetAsync(stats, 0, 128 * sizeof(float), stream);
        k_bn_stats<<<1024, 256, 0, stream>>>(bufA, stats);
        k_bn_coef<<<1, 64, 0, stream>>>(stats, bn_gamma + l * HD, bn_beta + l * HD,
                                        coef + l * 128);
    }

    hipMemsetAsync(pooled, 0, 64 * sizeof(float), stream);
    k_pool<<<1024, 256, 0, stream>>>(bufA, coef + 3 * 128, pooled);
    k_out<<<1, 64, 0, stream>>>(pooled, W_out, b_out, out);
}

// Round 9
// 973.452 us; speedup vs baseline: 1.3047x; 1.3047x over previous
//
#include <hip/hip_runtime.h>

#define N_NODES 100000
#define N_EDGES 1600000
#define F_IN    32
#define HD      64
#define EPS     1e-5f
#define SCAN_B  512
#define SCAN_G  ((N_NODES + SCAN_B - 1) / SCAN_B)   // 196
#define GROWS   16
#define NSHADOW 64

// ---------------- edge-index dtype probe ----------------
__global__ void k_detect(const int* __restrict__ ei, int* __restrict__ flag) {
    if (threadIdx.x == 0 && blockIdx.x == 0) {
        int all_zero = 1;
        for (int k = 0; k < 64; ++k)
            if (ei[2 * k + 1] != 0) { all_zero = 0; break; }
        *flag = all_zero;   // 1 -> int64 layout, 0 -> int32 layout
    }
}

__device__ __forceinline__ int load_src(const int* ei, int e, int is64) {
    return is64 ? ei[2 * e] : ei[e];
}
__device__ __forceinline__ int load_dst(const int* ei, int e, int is64) {
    return is64 ? ei[2 * (N_EDGES + e)] : ei[N_EDGES + e];
}

// ---------------- degree histogram + per-edge rank ----------------
__global__ void k_deg_rank(const int* __restrict__ ei, const int* __restrict__ flag,
                           int* __restrict__ deg, int* __restrict__ rank) {
    int e = blockIdx.x * blockDim.x + threadIdx.x;
    if (e >= N_EDGES) return;
    int is64 = *flag;
    rank[e] = atomicAdd(&deg[load_dst(ei, e, is64)], 1);
}

__global__ void k_dinv(const int* __restrict__ deg, float* __restrict__ dinv) {
    int n = blockIdx.x * blockDim.x + threadIdx.x;
    if (n >= N_NODES) return;
    dinv[n] = rsqrtf((float)deg[n] + 1.0f);
}

// ---------------- hierarchical scan ----------------
__global__ void k_scan1(const int* __restrict__ deg, int* __restrict__ bsum) {
    int t = threadIdx.x;
    int i = blockIdx.x * SCAN_B + t;
    __shared__ int ls[SCAN_B];
    ls[t] = (i < N_NODES) ? deg[i] : 0;
    __syncthreads();
    for (int off = SCAN_B / 2; off > 0; off >>= 1) {
        if (t < off) ls[t] += ls[t + off];
        __syncthreads();
    }
    if (t == 0) bsum[blockIdx.x] = ls[0];
}

__global__ void k_scan2(const int* __restrict__ bsum, int* __restrict__ boff,
                        int* __restrict__ row_start_last) {
    __shared__ int ls[256];
    int t = threadIdx.x;
    ls[t] = (t < SCAN_G) ? bsum[t] : 0;
    __syncthreads();
    for (int off = 1; off < 256; off <<= 1) {
        int u = (t >= off) ? ls[t - off] : 0;
        __syncthreads();
        ls[t] += u;
        __syncthreads();
    }
    boff[t] = (t == 0) ? 0 : ls[t - 1];
    if (t == 255) *row_start_last = ls[255];
}

__global__ void k_scan3(const int* __restrict__ deg, const int* __restrict__ boff,
                        int* __restrict__ row_start) {
    int t = threadIdx.x;
    int i = blockIdx.x * SCAN_B + t;
    int v = (i < N_NODES) ? deg[i] : 0;
    __shared__ int ls[SCAN_B];
    ls[t] = v;
    __syncthreads();
    for (int off = 1; off < SCAN_B; off <<= 1) {
        int u = (t >= off) ? ls[t - off] : 0;
        __syncthreads();
        ls[t] += u;
        __syncthreads();
    }
    if (i < N_NODES) row_start[i] = boff[blockIdx.x] + ls[t] - v;
}

// ---------------- bucket edges into CSR (atomic-free) ----------------
__global__ void k_bucket(const int* __restrict__ ei, const int* __restrict__ flag,
                         const int* __restrict__ row_start, const int* __restrict__ rank,
                         int* __restrict__ csr_src) {
    int e = blockIdx.x * blockDim.x + threadIdx.x;
    if (e >= N_EDGES) return;
    int is64 = *flag;
    int s = load_src(ei, e, is64);
    int d = load_dst(ei, e, is64);
    csr_src[row_start[d] + rank[e]] = s;
}

// ---------------- node embedding: h = x @ W_embed + b ----------------
__global__ void k_embed(const float* __restrict__ x, const float* __restrict__ W,
                        const float* __restrict__ b, float* __restrict__ h) {
    __shared__ float Ws[F_IN * HD];
    __shared__ float xs[4 * F_IN];
    int t = threadIdx.x;
    for (int i = t; i < F_IN * HD; i += 256) Ws[i] = W[i];
    if (t < 4 * F_IN) {
        int r = t >> 5, c = t & 31;
        int node = blockIdx.x * 4 + r;
        xs[t] = (node < N_NODES) ? x[node * F_IN + c] : 0.f;
    }
    __syncthreads();
    int r = t >> 6, j = t & 63;
    int node = blockIdx.x * 4 + r;
    float acc = b[j];
#pragma unroll
    for (int k = 0; k < F_IN; ++k)
        acc = fmaf(xs[r * F_IN + k], Ws[k * HD + j], acc);
    if (node < N_NODES) h[node * HD + j] = acc;
}

// ---------------- GEMM: C[n] = (relu(a*A[n]+c) @ W) * dinv[n] ----------------
__global__ void __launch_bounds__(256)
k_gemm64(const float* __restrict__ A, const float* __restrict__ W,
         const float* __restrict__ coef, const float* __restrict__ dinv,
         float* __restrict__ C) {
    __shared__ float Ws[HD * HD];     // 16 KB
    __shared__ float As[GROWS * HD];  // 4 KB
    int t = threadIdx.x;
    int base = blockIdx.x * GROWS;
    for (int i = t; i < HD * HD; i += 256) Ws[i] = W[i];
    for (int i = t; i < GROWS * HD; i += 256) {
        int r = i >> 6, c = i & 63;
        int node = base + r;
        float v = (node < N_NODES) ? A[node * HD + c] : 0.f;
        if (coef) v = fmaxf(fmaf(coef[c], v, coef[64 + c]), 0.f);
        As[i] = v;
    }
    __syncthreads();
    int r = t >> 6, j = t & 63;
    float acc0 = 0.f, acc1 = 0.f, acc2 = 0.f, acc3 = 0.f;
#pragma unroll
    for (int k = 0; k < HD; ++k) {
        float w = Ws[k * HD + j];
        acc0 = fmaf(As[(r     ) * HD + k], w, acc0);
        acc1 = fmaf(As[(r +  4) * HD + k], w, acc1);
        acc2 = fmaf(As[(r +  8) * HD + k], w, acc2);
        acc3 = fmaf(As[(r + 12) * HD + k], w, acc3);
    }
    int n0 = base + r;
    if (n0      < N_NODES) C[(n0     ) * HD + j] = acc0 * dinv[n0];
    if (n0 + 4  < N_NODES) C[(n0 +  4) * HD + j] = acc1 * dinv[n0 + 4];
    if (n0 + 8  < N_NODES) C[(n0 +  8) * HD + j] = acc2 * dinv[n0 + 8];
    if (n0 + 12 < N_NODES) C[(n0 + 12) * HD + j] = acc3 * dinv[n0 + 12];
}

// ---------------- CSR gather + fused BN stats ----------------
// 16 threads per node, thread owns one float4 column-quad. No shfl.
// h[n] = dinv[n]*(xw[n] + sum_e xw[src_e]) + cb; stats into NSHADOW shadow copies.
__global__ void __launch_bounds__(256)
k_gather_stats(const float4* __restrict__ xw4, const int* __restrict__ row_start,
               const int* __restrict__ csr_src, const float* __restrict__ dinv,
               const float* __restrict__ cb, float4* __restrict__ h4,
               float* __restrict__ stats_sh) {
    int t = threadIdx.x;
    int q = t & 15;          // float4 index within row
    int r = t >> 4;          // node within block
    int n = blockIdx.x * 16 + r;
    bool valid = (n < N_NODES);
    int beg = 0, end = 0;
    if (valid) { beg = row_start[n]; end = row_start[n + 1]; }
    float4 a0 = {0.f, 0.f, 0.f, 0.f}, a1 = {0.f, 0.f, 0.f, 0.f};
    if (valid) a0 = xw4[n * 16 + q];
    int e = beg;
    for (; e + 1 < end; e += 2) {
        int s0 = csr_src[e], s1 = csr_src[e + 1];
        float4 v0 = xw4[s0 * 16 + q];
        float4 v1 = xw4[s1 * 16 + q];
        a0.x += v0.x; a0.y += v0.y; a0.z += v0.z; a0.w += v0.w;
        a1.x += v1.x; a1.y += v1.y; a1.z += v1.z; a1.w += v1.w;
    }
    if (e < end) {
        int s0 = csr_src[e];
        float4 v0 = xw4[s0 * 16 + q];
        a0.x += v0.x; a0.y += v0.y; a0.z += v0.z; a0.w += v0.w;
    }
    float dn = valid ? dinv[n] : 0.f;
    float4 h;
    h.x = fmaf(a0.x + a1.x, dn, cb[q * 4 + 0]);
    h.y = fmaf(a0.y + a1.y, dn, cb[q * 4 + 1]);
    h.z = fmaf(a0.z + a1.z, dn, cb[q * 4 + 2]);
    h.w = fmaf(a0.w + a1.w, dn, cb[q * 4 + 3]);
    if (valid) h4[n * 16 + q] = h;

    // fused BN stats (sum, sumsq per column)
    float4 hs = valid ? h : make_float4(0.f, 0.f, 0.f, 0.f);
    __shared__ float4 ls_s[256], ls_q[256];   // 8 KB
    ls_s[t] = hs;
    float4 hq; hq.x = hs.x * hs.x; hq.y = hs.y * hs.y; hq.z = hs.z * hs.z; hq.w = hs.w * hs.w;
    ls_q[t] = hq;
    __syncthreads();
    if (t < 16) {
        float4 ss = ls_s[t], qq = ls_q[t];
        for (int rr = 1; rr < 16; ++rr) {
            float4 u = ls_s[rr * 16 + t], v = ls_q[rr * 16 + t];
            ss.x += u.x; ss.y += u.y; ss.z += u.z; ss.w += u.w;
            qq.x += v.x; qq.y += v.y; qq.z += v.z; qq.w += v.w;
        }
        float* sh = stats_sh + (blockIdx.x & (NSHADOW - 1)) * 128;
        atomicAdd(&sh[4 * t + 0], ss.x);
        atomicAdd(&sh[4 * t + 1], ss.y);
        atomicAdd(&sh[4 * t + 2], ss.z);
        atomicAdd(&sh[4 * t + 3], ss.w);
        atomicAdd(&sh[64 + 4 * t + 0], qq.x);
        atomicAdd(&sh[64 + 4 * t + 1], qq.y);
        atomicAdd(&sh[64 + 4 * t + 2], qq.z);
        atomicAdd(&sh[64 + 4 * t + 3], qq.w);
    }
}

// ---------------- shadow stats -> affine coef (a, c): bn(v) = a*v + c ----------------
__global__ void k_bn_coef(const float* __restrict__ stats_sh, const float* __restrict__ gamma,
                          const float* __restrict__ beta, float* __restrict__ coef) {
    int j = threadIdx.x;   // 64
    float s = 0.f, s2 = 0.f;
    for (int c = 0; c < NSHADOW; ++c) {
        s  += stats_sh[c * 128 + j];
        s2 += stats_sh[c * 128 + 64 + j];
    }
    float mu  = s * (1.0f / N_NODES);
    float var = s2 * (1.0f / N_NODES) - mu * mu;
    float rs  = rsqrtf(var + EPS);
    float a   = gamma[j] * rs;
    coef[j]      = a;
    coef[64 + j] = fmaf(-a, mu, beta[j]);
}

// ---------------- mean pool with fused BN+ReLU ----------------
__global__ void k_pool(const float* __restrict__ h, const float* __restrict__ coef,
                       float* __restrict__ pooled) {
    int t = threadIdx.x;
    int j = t & 63, rg = t >> 6;
    float a = coef[j], c = coef[64 + j];
    float s = 0.f;
    for (int n = blockIdx.x * 4 + rg; n < N_NODES; n += gridDim.x * 4)
        s += fmaxf(fmaf(a, h[n * HD + j], c), 0.f);
    __shared__ float ls[256];
    ls[t] = s;
    __syncthreads();
    if (t < 64)
        atomicAdd(&pooled[j], ls[t] + ls[t + 64] + ls[t + 128] + ls[t + 192]);
}

// ---------------- output ----------------
__global__ void k_out(const float* __restrict__ pooled, const float* __restrict__ Wout,
                      const float* __restrict__ bout, float* __restrict__ out) {
    int o = threadIdx.x;
    float acc = bout[o];
#pragma unroll
    for (int k = 0; k < HD; ++k)
        acc = fmaf(pooled[k] * (1.0f / N_NODES), Wout[k * HD + o], acc);
    out[o] = acc;
}

extern "C" void kernel_launch(void* const* d_in, const int* in_sizes, int n_in,
                              void* d_out, int out_size, void* d_ws, size_t ws_size,
                              hipStream_t stream) {
    const float* x        = (const float*)d_in[0];
    const int*   ei       = (const int*)  d_in[1];
    const float* W_embed  = (const float*)d_in[2];
    const float* b_embed  = (const float*)d_in[3];
    const float* conv_W   = (const float*)d_in[4];
    const float* conv_b   = (const float*)d_in[5];
    const float* bn_gamma = (const float*)d_in[6];
    const float* bn_beta  = (const float*)d_in[7];
    const float* W_out    = (const float*)d_in[8];
    const float* b_out    = (const float*)d_in[9];
    float* out = (float*)d_out;

    float* ws = (float*)d_ws;
    int*   deg       = (int*)ws;                          // N
    float* dinv      = ws + N_NODES;                      // N
    int*   row_start = (int*)(ws + 2 * N_NODES);          // N+1 (pad 8)
    float* small     = ws + 3 * N_NODES + 8;
    int*   bsum      = (int*)small;                       // 256
    int*   boff      = (int*)(small + 256);               // 256
    float* stats_sh  = small + 512;                       // NSHADOW*128 = 8192
    float* pooled    = small + 8704;                      // 64
    float* coef      = small + 8768;                      // 4*128 = 512
    int*   flag      = (int*)(small + 9280);              // 1 (pad 64)
    int*   csr_src   = (int*)(small + 9344);              // E
    float* bufA      = small + 9344 + N_EDGES;            // N*64
    float* bufB      = bufA + N_NODES * HD;               // N*64
    int*   rank      = (int*)bufB;                        // E (aliases bufB, pre-GEMM only)

    hipMemsetAsync(deg, 0, N_NODES * sizeof(int), stream);
    k_detect<<<1, 64, 0, stream>>>(ei, flag);
    k_deg_rank<<<(N_EDGES + 255) / 256, 256, 0, stream>>>(ei, flag, deg, rank);
    k_dinv<<<(N_NODES + 255) / 256, 256, 0, stream>>>(deg, dinv);
    k_scan1<<<SCAN_G, SCAN_B, 0, stream>>>(deg, bsum);
    k_scan2<<<1, 256, 0, stream>>>(bsum, boff, ((int*)(ws + 2 * N_NODES)) + N_NODES);
    k_scan3<<<SCAN_G, SCAN_B, 0, stream>>>(deg, boff, row_start);
    k_embed<<<(N_NODES + 3) / 4, 256, 0, stream>>>(x, W_embed, b_embed, bufA);
    k_bucket<<<(N_EDGES + 255) / 256, 256, 0, stream>>>(ei, flag, row_start, rank, csr_src);

    for (int l = 0; l < 4; ++l) {
        k_gemm64<<<(N_NODES + GROWS - 1) / GROWS, 256, 0, stream>>>(
            bufA, conv_W + l * HD * HD, l ? coef + (l - 1) * 128 : nullptr, dinv, bufB);
        hipMemsetAsync(stats_sh, 0, NSHADOW * 128 * sizeof(float), stream);
        k_gather_stats<<<(N_NODES + 15) / 16, 256, 0, stream>>>(
            (const float4*)bufB, row_start, csr_src, dinv, conv_b + l * HD,
            (float4*)bufA, stats_sh);
        k_bn_coef<<<1, 64, 0, stream>>>(stats_sh, bn_gamma + l * HD, bn_beta + l * HD,
                                        coef + l * 128);
    }

    hipMemsetAsync(pooled, 0, 64 * sizeof(float), stream);
    k_pool<<<1024, 256, 0, stream>>>(bufA, coef + 3 * 128, pooled);
    k_out<<<1, 64, 0, stream>>>(pooled, W_out, b_out, out);
}

// Round 10
// 664.042 us; speedup vs baseline: 1.9126x; 1.4660x over previous
//
#include <hip/hip_runtime.h>

#define N_NODES 100000
#define N_EDGES 1600000
#define F_IN    32
#define HD      64
#define EPS     1e-5f
#define SCAN_B  512
#define SCAN_G  ((N_NODES + SCAN_B - 1) / SCAN_B)   // 196
#define NSHADOW 64
#define BM      128
#define PADR    129   // As_t per-k row stride (129 mod 32 == 1 -> bank spread)

// ---------------- edge-index dtype probe ----------------
__global__ void k_detect(const int* __restrict__ ei, int* __restrict__ flag) {
    if (threadIdx.x == 0 && blockIdx.x == 0) {
        int all_zero = 1;
        for (int k = 0; k < 64; ++k)
            if (ei[2 * k + 1] != 0) { all_zero = 0; break; }
        *flag = all_zero;   // 1 -> int64 layout, 0 -> int32 layout
    }
}

__device__ __forceinline__ int load_src(const int* ei, int e, int is64) {
    return is64 ? ei[2 * e] : ei[e];
}
__device__ __forceinline__ int load_dst(const int* ei, int e, int is64) {
    return is64 ? ei[2 * (N_EDGES + e)] : ei[N_EDGES + e];
}

// ---------------- degree histogram + per-edge rank ----------------
__global__ void k_deg_rank(const int* __restrict__ ei, const int* __restrict__ flag,
                           int* __restrict__ deg, int* __restrict__ rank) {
    int e = blockIdx.x * blockDim.x + threadIdx.x;
    if (e >= N_EDGES) return;
    int is64 = *flag;
    rank[e] = atomicAdd(&deg[load_dst(ei, e, is64)], 1);
}

__global__ void k_dinv(const int* __restrict__ deg, float* __restrict__ dinv) {
    int n = blockIdx.x * blockDim.x + threadIdx.x;
    if (n >= N_NODES) return;
    dinv[n] = rsqrtf((float)deg[n] + 1.0f);
}

// ---------------- hierarchical scan ----------------
__global__ void k_scan1(const int* __restrict__ deg, int* __restrict__ bsum) {
    int t = threadIdx.x;
    int i = blockIdx.x * SCAN_B + t;
    __shared__ int ls[SCAN_B];
    ls[t] = (i < N_NODES) ? deg[i] : 0;
    __syncthreads();
    for (int off = SCAN_B / 2; off > 0; off >>= 1) {
        if (t < off) ls[t] += ls[t + off];
        __syncthreads();
    }
    if (t == 0) bsum[blockIdx.x] = ls[0];
}

__global__ void k_scan2(const int* __restrict__ bsum, int* __restrict__ boff,
                        int* __restrict__ row_start_last) {
    __shared__ int ls[256];
    int t = threadIdx.x;
    ls[t] = (t < SCAN_G) ? bsum[t] : 0;
    __syncthreads();
    for (int off = 1; off < 256; off <<= 1) {
        int u = (t >= off) ? ls[t - off] : 0;
        __syncthreads();
        ls[t] += u;
        __syncthreads();
    }
    boff[t] = (t == 0) ? 0 : ls[t - 1];
    if (t == 255) *row_start_last = ls[255];
}

__global__ void k_scan3(const int* __restrict__ deg, const int* __restrict__ boff,
                        int* __restrict__ row_start) {
    int t = threadIdx.x;
    int i = blockIdx.x * SCAN_B + t;
    int v = (i < N_NODES) ? deg[i] : 0;
    __shared__ int ls[SCAN_B];
    ls[t] = v;
    __syncthreads();
    for (int off = 1; off < SCAN_B; off <<= 1) {
        int u = (t >= off) ? ls[t - off] : 0;
        __syncthreads();
        ls[t] += u;
        __syncthreads();
    }
    if (i < N_NODES) row_start[i] = boff[blockIdx.x] + ls[t] - v;
}

// ---------------- bucket edges into CSR (atomic-free) ----------------
__global__ void k_bucket(const int* __restrict__ ei, const int* __restrict__ flag,
                         const int* __restrict__ row_start, const int* __restrict__ rank,
                         int* __restrict__ csr_src) {
    int e = blockIdx.x * blockDim.x + threadIdx.x;
    if (e >= N_EDGES) return;
    int is64 = *flag;
    int s = load_src(ei, e, is64);
    int d = load_dst(ei, e, is64);
    csr_src[row_start[d] + rank[e]] = s;
}

// ---------------- node embedding: h = x @ W_embed + b ----------------
__global__ void k_embed(const float* __restrict__ x, const float* __restrict__ W,
                        const float* __restrict__ b, float* __restrict__ h) {
    __shared__ float Ws[F_IN * HD];
    __shared__ float xs[4 * F_IN];
    int t = threadIdx.x;
    for (int i = t; i < F_IN * HD; i += 256) Ws[i] = W[i];
    if (t < 4 * F_IN) {
        int r = t >> 5, c = t & 31;
        int node = blockIdx.x * 4 + r;
        xs[t] = (node < N_NODES) ? x[node * F_IN + c] : 0.f;
    }
    __syncthreads();
    int r = t >> 6, j = t & 63;
    int node = blockIdx.x * 4 + r;
    float acc = b[j];
#pragma unroll
    for (int k = 0; k < F_IN; ++k)
        acc = fmaf(xs[r * F_IN + k], Ws[k * HD + j], acc);
    if (node < N_NODES) h[node * HD + j] = acc;
}

// ---------------- GEMM: C[n] = (relu(a*A[n]+c) @ W) * dinv[n] ----------------
// BM=128 rows/block, 256 threads, 8x4 register tile per thread.
// A staged TRANSPOSED in LDS (As_t[k][row], stride PADR) so per-k reads are
// conflict-free b32 broadcasts; W read as b128 quads.
__global__ void __launch_bounds__(256)
k_gemm128(const float4* __restrict__ A4, const float* __restrict__ W,
          const float* __restrict__ coef, const float* __restrict__ dinv,
          float4* __restrict__ C4) {
    __shared__ float Ws[HD * HD];        // 16 KB, [k][j]
    __shared__ float As_t[HD * PADR];    // 33 KB, [k][row]
    int t = threadIdx.x;
    int base = blockIdx.x * BM;

    // stage W (row-major copy, float4)
    for (int i = t; i < HD * HD / 4; i += 256)
        ((float4*)Ws)[i] = ((const float4*)W)[i];

    // stage A transposed, applying BN-affine+ReLU of previous layer
    bool has_coef = (coef != nullptr);
    for (int iter = 0; iter < 8; ++iter) {
        int flat = t + iter * 256;      // 0..2047
        int row = flat >> 4;            // 0..127
        int q = flat & 15;              // float4 col-quad
        int node = base + row;
        float4 v = {0.f, 0.f, 0.f, 0.f};
        if (node < N_NODES) v = A4[node * 16 + q];
        if (has_coef) {
            float4 ca = ((const float4*)coef)[q];
            float4 cc = ((const float4*)(coef + 64))[q];
            v.x = fmaxf(fmaf(ca.x, v.x, cc.x), 0.f);
            v.y = fmaxf(fmaf(ca.y, v.y, cc.y), 0.f);
            v.z = fmaxf(fmaf(ca.z, v.z, cc.z), 0.f);
            v.w = fmaxf(fmaf(ca.w, v.w, cc.w), 0.f);
        }
        As_t[(4 * q + 0) * PADR + row] = v.x;
        As_t[(4 * q + 1) * PADR + row] = v.y;
        As_t[(4 * q + 2) * PADR + row] = v.z;
        As_t[(4 * q + 3) * PADR + row] = v.w;
    }
    __syncthreads();

    int colgrp = t & 15;    // output cols 4*colgrp..+3
    int rowgrp = t >> 4;    // output rows rowgrp + 16*u, u=0..7
    float4 acc[8];
#pragma unroll
    for (int u = 0; u < 8; ++u) acc[u] = make_float4(0.f, 0.f, 0.f, 0.f);

    const float4* Ws4 = (const float4*)Ws;
    for (int k = 0; k < HD; ++k) {
        float4 wv = Ws4[k * 16 + colgrp];
        const float* at = As_t + k * PADR + rowgrp;
#pragma unroll
        for (int u = 0; u < 8; ++u) {
            float av = at[16 * u];
            acc[u].x = fmaf(av, wv.x, acc[u].x);
            acc[u].y = fmaf(av, wv.y, acc[u].y);
            acc[u].z = fmaf(av, wv.z, acc[u].z);
            acc[u].w = fmaf(av, wv.w, acc[u].w);
        }
    }

#pragma unroll
    for (int u = 0; u < 8; ++u) {
        int node = base + rowgrp + 16 * u;
        if (node < N_NODES) {
            float dn = dinv[node];
            float4 o = acc[u];
            o.x *= dn; o.y *= dn; o.z *= dn; o.w *= dn;
            C4[node * 16 + colgrp] = o;
        }
    }
}

// ---------------- CSR gather + fused BN stats ----------------
__global__ void __launch_bounds__(256)
k_gather_stats(const float4* __restrict__ xw4, const int* __restrict__ row_start,
               const int* __restrict__ csr_src, const float* __restrict__ dinv,
               const float* __restrict__ cb, float4* __restrict__ h4,
               float* __restrict__ stats_sh) {
    int t = threadIdx.x;
    int q = t & 15;          // float4 index within row
    int r = t >> 4;          // node within block
    int n = blockIdx.x * 16 + r;
    bool valid = (n < N_NODES);
    int beg = 0, end = 0;
    if (valid) { beg = row_start[n]; end = row_start[n + 1]; }
    float4 a0 = {0.f, 0.f, 0.f, 0.f}, a1 = {0.f, 0.f, 0.f, 0.f};
    if (valid) a0 = xw4[n * 16 + q];
    int e = beg;
    for (; e + 1 < end; e += 2) {
        int s0 = csr_src[e], s1 = csr_src[e + 1];
        float4 v0 = xw4[s0 * 16 + q];
        float4 v1 = xw4[s1 * 16 + q];
        a0.x += v0.x; a0.y += v0.y; a0.z += v0.z; a0.w += v0.w;
        a1.x += v1.x; a1.y += v1.y; a1.z += v1.z; a1.w += v1.w;
    }
    if (e < end) {
        int s0 = csr_src[e];
        float4 v0 = xw4[s0 * 16 + q];
        a0.x += v0.x; a0.y += v0.y; a0.z += v0.z; a0.w += v0.w;
    }
    float dn = valid ? dinv[n] : 0.f;
    float4 h;
    h.x = fmaf(a0.x + a1.x, dn, cb[q * 4 + 0]);
    h.y = fmaf(a0.y + a1.y, dn, cb[q * 4 + 1]);
    h.z = fmaf(a0.z + a1.z, dn, cb[q * 4 + 2]);
    h.w = fmaf(a0.w + a1.w, dn, cb[q * 4 + 3]);
    if (valid) h4[n * 16 + q] = h;

    // fused BN stats (sum, sumsq per column)
    float4 hs = valid ? h : make_float4(0.f, 0.f, 0.f, 0.f);
    __shared__ float4 ls_s[256], ls_q[256];   // 8 KB
    ls_s[t] = hs;
    float4 hq; hq.x = hs.x * hs.x; hq.y = hs.y * hs.y; hq.z = hs.z * hs.z; hq.w = hs.w * hs.w;
    ls_q[t] = hq;
    __syncthreads();
    if (t < 16) {
        float4 ss = ls_s[t], qq = ls_q[t];
        for (int rr = 1; rr < 16; ++rr) {
            float4 u = ls_s[rr * 16 + t], v = ls_q[rr * 16 + t];
            ss.x += u.x; ss.y += u.y; ss.z += u.z; ss.w += u.w;
            qq.x += v.x; qq.y += v.y; qq.z += v.z; qq.w += v.w;
        }
        float* sh = stats_sh + (blockIdx.x & (NSHADOW - 1)) * 128;
        atomicAdd(&sh[4 * t + 0], ss.x);
        atomicAdd(&sh[4 * t + 1], ss.y);
        atomicAdd(&sh[4 * t + 2], ss.z);
        atomicAdd(&sh[4 * t + 3], ss.w);
        atomicAdd(&sh[64 + 4 * t + 0], qq.x);
        atomicAdd(&sh[64 + 4 * t + 1], qq.y);
        atomicAdd(&sh[64 + 4 * t + 2], qq.z);
        atomicAdd(&sh[64 + 4 * t + 3], qq.w);
    }
}

// ---------------- shadow stats -> affine coef (a, c): bn(v) = a*v + c ----------------
__global__ void k_bn_coef(const float* __restrict__ stats_sh, const float* __restrict__ gamma,
                          const float* __restrict__ beta, float* __restrict__ coef) {
    int j = threadIdx.x;   // 64
    float s = 0.f, s2 = 0.f;
    for (int c = 0; c < NSHADOW; ++c) {
        s  += stats_sh[c * 128 + j];
        s2 += stats_sh[c * 128 + 64 + j];
    }
    float mu  = s * (1.0f / N_NODES);
    float var = s2 * (1.0f / N_NODES) - mu * mu;
    float rs  = rsqrtf(var + EPS);
    float a   = gamma[j] * rs;
    coef[j]      = a;
    coef[64 + j] = fmaf(-a, mu, beta[j]);
}

// ---------------- mean pool with fused BN+ReLU ----------------
__global__ void k_pool(const float* __restrict__ h, const float* __restrict__ coef,
                       float* __restrict__ pooled) {
    int t = threadIdx.x;
    int j = t & 63, rg = t >> 6;
    float a = coef[j], c = coef[64 + j];
    float s = 0.f;
    for (int n = blockIdx.x * 4 + rg; n < N_NODES; n += gridDim.x * 4)
        s += fmaxf(fmaf(a, h[n * HD + j], c), 0.f);
    __shared__ float ls[256];
    ls[t] = s;
    __syncthreads();
    if (t < 64)
        atomicAdd(&pooled[j], ls[t] + ls[t + 64] + ls[t + 128] + ls[t + 192]);
}

// ---------------- output ----------------
__global__ void k_out(const float* __restrict__ pooled, const float* __restrict__ Wout,
                      const float* __restrict__ bout, float* __restrict__ out) {
    int o = threadIdx.x;
    float acc = bout[o];
#pragma unroll
    for (int k = 0; k < HD; ++k)
        acc = fmaf(pooled[k] * (1.0f / N_NODES), Wout[k * HD + o], acc);
    out[o] = acc;
}

extern "C" void kernel_launch(void* const* d_in, const int* in_sizes, int n_in,
                              void* d_out, int out_size, void* d_ws, size_t ws_size,
                              hipStream_t stream) {
    const float* x        = (const float*)d_in[0];
    const int*   ei       = (const int*)  d_in[1];
    const float* W_embed  = (const float*)d_in[2];
    const float* b_embed  = (const float*)d_in[3];
    const float* conv_W   = (const float*)d_in[4];
    const float* conv_b   = (const float*)d_in[5];
    const float* bn_gamma = (const float*)d_in[6];
    const float* bn_beta  = (const float*)d_in[7];
    const float* W_out    = (const float*)d_in[8];
    const float* b_out    = (const float*)d_in[9];
    float* out = (float*)d_out;

    float* ws = (float*)d_ws;
    int*   deg       = (int*)ws;                          // N
    float* dinv      = ws + N_NODES;                      // N
    int*   row_start = (int*)(ws + 2 * N_NODES);          // N+1 (pad 8)
    float* small     = ws + 3 * N_NODES + 8;
    int*   bsum      = (int*)small;                       // 256
    int*   boff      = (int*)(small + 256);               // 256
    float* stats_sh  = small + 512;                       // NSHADOW*128 = 8192
    float* pooled    = small + 8704;                      // 64
    float* coef      = small + 8768;                      // 4*128 = 512
    int*   flag      = (int*)(small + 9280);              // 1 (pad 64)
    int*   csr_src   = (int*)(small + 9344);              // E
    float* bufA      = small + 9344 + N_EDGES;            // N*64
    float* bufB      = bufA + N_NODES * HD;               // N*64
    int*   rank      = (int*)bufB;                        // E (aliases bufB, pre-GEMM only)

    hipMemsetAsync(deg, 0, N_NODES * sizeof(int), stream);
    k_detect<<<1, 64, 0, stream>>>(ei, flag);
    k_deg_rank<<<(N_EDGES + 255) / 256, 256, 0, stream>>>(ei, flag, deg, rank);
    k_dinv<<<(N_NODES + 255) / 256, 256, 0, stream>>>(deg, dinv);
    k_scan1<<<SCAN_G, SCAN_B, 0, stream>>>(deg, bsum);
    k_scan2<<<1, 256, 0, stream>>>(bsum, boff, ((int*)(ws + 2 * N_NODES)) + N_NODES);
    k_scan3<<<SCAN_G, SCAN_B, 0, stream>>>(deg, boff, row_start);
    k_embed<<<(N_NODES + 3) / 4, 256, 0, stream>>>(x, W_embed, b_embed, bufA);
    k_bucket<<<(N_EDGES + 255) / 256, 256, 0, stream>>>(ei, flag, row_start, rank, csr_src);

    for (int l = 0; l < 4; ++l) {
        k_gemm128<<<(N_NODES + BM - 1) / BM, 256, 0, stream>>>(
            (const float4*)bufA, conv_W + l * HD * HD,
            l ? coef + (l - 1) * 128 : nullptr, dinv, (float4*)bufB);
        hipMemsetAsync(stats_sh, 0, NSHADOW * 128 * sizeof(float), stream);
        k_gather_stats<<<(N_NODES + 15) / 16, 256, 0, stream>>>(
            (const float4*)bufB, row_start, csr_src, dinv, conv_b + l * HD,
            (float4*)bufA, stats_sh);
        k_bn_coef<<<1, 64, 0, stream>>>(stats_sh, bn_gamma + l * HD, bn_beta + l * HD,
                                        coef + l * 128);
    }

    hipMemsetAsync(pooled, 0, 64 * sizeof(float), stream);
    k_pool<<<1024, 256, 0, stream>>>(bufA, coef + 3 * 128, pooled);
    k_out<<<1, 64, 0, stream>>>(pooled, W_out, b_out, out);
}

// Round 11
// 548.384 us; speedup vs baseline: 2.3159x; 1.2109x over previous
//
#include <hip/hip_runtime.h>

#define N_NODES 100000
#define N_EDGES 1600000
#define F_IN    32
#define HD      64
#define EPS     1e-5f
#define SCAN_B  512
#define SCAN_G  ((N_NODES + SCAN_B - 1) / SCAN_B)   // 196
#define NSHADOW 64
#define BM      128
#define PADR    129   // As_t per-k row stride (129 mod 32 == 1 -> bank spread)

// bf16 round-to-nearest-even pack/unpack
__device__ __forceinline__ unsigned bf16r(float f) {
    unsigned u = __float_as_uint(f);
    return (u + 0x7fffu + ((u >> 16) & 1u)) >> 16;
}
__device__ __forceinline__ unsigned pack2(float lo, float hi) {
    return bf16r(lo) | (bf16r(hi) << 16);
}
__device__ __forceinline__ float unlo(unsigned u) { return __uint_as_float(u << 16); }
__device__ __forceinline__ float unhi(unsigned u) { return __uint_as_float(u & 0xffff0000u); }

// ---------------- edge-index dtype probe ----------------
__global__ void k_detect(const int* __restrict__ ei, int* __restrict__ flag) {
    if (threadIdx.x == 0 && blockIdx.x == 0) {
        int all_zero = 1;
        for (int k = 0; k < 64; ++k)
            if (ei[2 * k + 1] != 0) { all_zero = 0; break; }
        *flag = all_zero;   // 1 -> int64 layout, 0 -> int32 layout
    }
}

__device__ __forceinline__ int load_src(const int* ei, int e, int is64) {
    return is64 ? ei[2 * e] : ei[e];
}
__device__ __forceinline__ int load_dst(const int* ei, int e, int is64) {
    return is64 ? ei[2 * (N_EDGES + e)] : ei[N_EDGES + e];
}

// ---------------- degree histogram + per-edge rank ----------------
__global__ void k_deg_rank(const int* __restrict__ ei, const int* __restrict__ flag,
                           int* __restrict__ deg, int* __restrict__ rank) {
    int e = blockIdx.x * blockDim.x + threadIdx.x;
    if (e >= N_EDGES) return;
    int is64 = *flag;
    rank[e] = atomicAdd(&deg[load_dst(ei, e, is64)], 1);
}

__global__ void k_dinv(const int* __restrict__ deg, float* __restrict__ dinv) {
    int n = blockIdx.x * blockDim.x + threadIdx.x;
    if (n >= N_NODES) return;
    dinv[n] = rsqrtf((float)deg[n] + 1.0f);
}

// ---------------- hierarchical scan ----------------
__global__ void k_scan1(const int* __restrict__ deg, int* __restrict__ bsum) {
    int t = threadIdx.x;
    int i = blockIdx.x * SCAN_B + t;
    __shared__ int ls[SCAN_B];
    ls[t] = (i < N_NODES) ? deg[i] : 0;
    __syncthreads();
    for (int off = SCAN_B / 2; off > 0; off >>= 1) {
        if (t < off) ls[t] += ls[t + off];
        __syncthreads();
    }
    if (t == 0) bsum[blockIdx.x] = ls[0];
}

__global__ void k_scan2(const int* __restrict__ bsum, int* __restrict__ boff,
                        int* __restrict__ row_start_last) {
    __shared__ int ls[256];
    int t = threadIdx.x;
    ls[t] = (t < SCAN_G) ? bsum[t] : 0;
    __syncthreads();
    for (int off = 1; off < 256; off <<= 1) {
        int u = (t >= off) ? ls[t - off] : 0;
        __syncthreads();
        ls[t] += u;
        __syncthreads();
    }
    boff[t] = (t == 0) ? 0 : ls[t - 1];
    if (t == 255) *row_start_last = ls[255];
}

__global__ void k_scan3(const int* __restrict__ deg, const int* __restrict__ boff,
                        int* __restrict__ row_start) {
    int t = threadIdx.x;
    int i = blockIdx.x * SCAN_B + t;
    int v = (i < N_NODES) ? deg[i] : 0;
    __shared__ int ls[SCAN_B];
    ls[t] = v;
    __syncthreads();
    for (int off = 1; off < SCAN_B; off <<= 1) {
        int u = (t >= off) ? ls[t - off] : 0;
        __syncthreads();
        ls[t] += u;
        __syncthreads();
    }
    if (i < N_NODES) row_start[i] = boff[blockIdx.x] + ls[t] - v;
}

// ---------------- bucket edges into CSR (atomic-free) ----------------
__global__ void k_bucket(const int* __restrict__ ei, const int* __restrict__ flag,
                         const int* __restrict__ row_start, const int* __restrict__ rank,
                         int* __restrict__ csr_src) {
    int e = blockIdx.x * blockDim.x + threadIdx.x;
    if (e >= N_EDGES) return;
    int is64 = *flag;
    int s = load_src(ei, e, is64);
    int d = load_dst(ei, e, is64);
    csr_src[row_start[d] + rank[e]] = s;
}

// ---------------- node embedding: h = x @ W_embed + b ----------------
__global__ void k_embed(const float* __restrict__ x, const float* __restrict__ W,
                        const float* __restrict__ b, float* __restrict__ h) {
    __shared__ float Ws[F_IN * HD];
    __shared__ float xs[4 * F_IN];
    int t = threadIdx.x;
    for (int i = t; i < F_IN * HD; i += 256) Ws[i] = W[i];
    if (t < 4 * F_IN) {
        int r = t >> 5, c = t & 31;
        int node = blockIdx.x * 4 + r;
        xs[t] = (node < N_NODES) ? x[node * F_IN + c] : 0.f;
    }
    __syncthreads();
    int r = t >> 6, j = t & 63;
    int node = blockIdx.x * 4 + r;
    float acc = b[j];
#pragma unroll
    for (int k = 0; k < F_IN; ++k)
        acc = fmaf(xs[r * F_IN + k], Ws[k * HD + j], acc);
    if (node < N_NODES) h[node * HD + j] = acc;
}

// ---------------- GEMM: Cb[n] = bf16((relu(a*A[n]+c) @ W) * dinv[n]) ----------------
// BM=128 rows/block, 256 threads, 8x4 register tile per thread. Output packed bf16x2.
__global__ void __launch_bounds__(256)
k_gemm128(const float4* __restrict__ A4, const float* __restrict__ W,
          const float* __restrict__ coef, const float* __restrict__ dinv,
          uint2* __restrict__ Cb) {
    __shared__ float Ws[HD * HD];        // 16 KB, [k][j]
    __shared__ float As_t[HD * PADR];    // 33 KB, [k][row]
    int t = threadIdx.x;
    int base = blockIdx.x * BM;

    for (int i = t; i < HD * HD / 4; i += 256)
        ((float4*)Ws)[i] = ((const float4*)W)[i];

    bool has_coef = (coef != nullptr);
    for (int iter = 0; iter < 8; ++iter) {
        int flat = t + iter * 256;      // 0..2047
        int row = flat >> 4;            // 0..127
        int q = flat & 15;              // float4 col-quad
        int node = base + row;
        float4 v = {0.f, 0.f, 0.f, 0.f};
        if (node < N_NODES) v = A4[node * 16 + q];
        if (has_coef) {
            float4 ca = ((const float4*)coef)[q];
            float4 cc = ((const float4*)(coef + 64))[q];
            v.x = fmaxf(fmaf(ca.x, v.x, cc.x), 0.f);
            v.y = fmaxf(fmaf(ca.y, v.y, cc.y), 0.f);
            v.z = fmaxf(fmaf(ca.z, v.z, cc.z), 0.f);
            v.w = fmaxf(fmaf(ca.w, v.w, cc.w), 0.f);
        }
        As_t[(4 * q + 0) * PADR + row] = v.x;
        As_t[(4 * q + 1) * PADR + row] = v.y;
        As_t[(4 * q + 2) * PADR + row] = v.z;
        As_t[(4 * q + 3) * PADR + row] = v.w;
    }
    __syncthreads();

    int colgrp = t & 15;    // output cols 4*colgrp..+3
    int rowgrp = t >> 4;    // output rows rowgrp + 16*u
    float4 acc[8];
#pragma unroll
    for (int u = 0; u < 8; ++u) acc[u] = make_float4(0.f, 0.f, 0.f, 0.f);

    const float4* Ws4 = (const float4*)Ws;
    for (int k = 0; k < HD; ++k) {
        float4 wv = Ws4[k * 16 + colgrp];
        const float* at = As_t + k * PADR + rowgrp;
#pragma unroll
        for (int u = 0; u < 8; ++u) {
            float av = at[16 * u];
            acc[u].x = fmaf(av, wv.x, acc[u].x);
            acc[u].y = fmaf(av, wv.y, acc[u].y);
            acc[u].z = fmaf(av, wv.z, acc[u].z);
            acc[u].w = fmaf(av, wv.w, acc[u].w);
        }
    }

#pragma unroll
    for (int u = 0; u < 8; ++u) {
        int node = base + rowgrp + 16 * u;
        if (node < N_NODES) {
            float dn = dinv[node];
            float4 o = acc[u];
            uint2 p;
            p.x = pack2(o.x * dn, o.y * dn);
            p.y = pack2(o.z * dn, o.w * dn);
            Cb[node * 16 + colgrp] = p;
        }
    }
}

// ---------------- CSR gather (bf16 messages) + fused BN stats ----------------
// 16 threads/node; thread q owns cols 4q..4q+3 (one uint2 = 4 bf16 per row).
__global__ void __launch_bounds__(256)
k_gather_stats(const uint2* __restrict__ xwb, const int* __restrict__ row_start,
               const int* __restrict__ csr_src, const float* __restrict__ dinv,
               const float* __restrict__ cb, float4* __restrict__ h4,
               float* __restrict__ stats_sh) {
    int t = threadIdx.x;
    int q = t & 15;
    int r = t >> 4;
    int n = blockIdx.x * 16 + r;
    bool valid = (n < N_NODES);
    int beg = 0, end = 0;
    if (valid) { beg = row_start[n]; end = row_start[n + 1]; }
    float4 a0 = {0.f, 0.f, 0.f, 0.f}, a1 = {0.f, 0.f, 0.f, 0.f};
    if (valid) {
        uint2 p = xwb[n * 16 + q];
        a0.x = unlo(p.x); a0.y = unhi(p.x); a0.z = unlo(p.y); a0.w = unhi(p.y);
    }
    int e = beg;
    for (; e + 1 < end; e += 2) {
        int s0 = csr_src[e], s1 = csr_src[e + 1];
        uint2 p0 = xwb[s0 * 16 + q];
        uint2 p1 = xwb[s1 * 16 + q];
        a0.x += unlo(p0.x); a0.y += unhi(p0.x); a0.z += unlo(p0.y); a0.w += unhi(p0.y);
        a1.x += unlo(p1.x); a1.y += unhi(p1.x); a1.z += unlo(p1.y); a1.w += unhi(p1.y);
    }
    if (e < end) {
        int s0 = csr_src[e];
        uint2 p0 = xwb[s0 * 16 + q];
        a0.x += unlo(p0.x); a0.y += unhi(p0.x); a0.z += unlo(p0.y); a0.w += unhi(p0.y);
    }
    float dn = valid ? dinv[n] : 0.f;
    float4 h;
    h.x = fmaf(a0.x + a1.x, dn, cb[q * 4 + 0]);
    h.y = fmaf(a0.y + a1.y, dn, cb[q * 4 + 1]);
    h.z = fmaf(a0.z + a1.z, dn, cb[q * 4 + 2]);
    h.w = fmaf(a0.w + a1.w, dn, cb[q * 4 + 3]);
    if (valid) h4[n * 16 + q] = h;

    // fused BN stats (sum, sumsq per column)
    float4 hs = valid ? h : make_float4(0.f, 0.f, 0.f, 0.f);
    __shared__ float4 ls_s[256], ls_q[256];   // 8 KB
    ls_s[t] = hs;
    float4 hq; hq.x = hs.x * hs.x; hq.y = hs.y * hs.y; hq.z = hs.z * hs.z; hq.w = hs.w * hs.w;
    ls_q[t] = hq;
    __syncthreads();
    if (t < 16) {
        float4 ss = ls_s[t], qq = ls_q[t];
        for (int rr = 1; rr < 16; ++rr) {
            float4 u = ls_s[rr * 16 + t], v = ls_q[rr * 16 + t];
            ss.x += u.x; ss.y += u.y; ss.z += u.z; ss.w += u.w;
            qq.x += v.x; qq.y += v.y; qq.z += v.z; qq.w += v.w;
        }
        float* sh = stats_sh + (blockIdx.x & (NSHADOW - 1)) * 128;
        atomicAdd(&sh[4 * t + 0], ss.x);
        atomicAdd(&sh[4 * t + 1], ss.y);
        atomicAdd(&sh[4 * t + 2], ss.z);
        atomicAdd(&sh[4 * t + 3], ss.w);
        atomicAdd(&sh[64 + 4 * t + 0], qq.x);
        atomicAdd(&sh[64 + 4 * t + 1], qq.y);
        atomicAdd(&sh[64 + 4 * t + 2], qq.z);
        atomicAdd(&sh[64 + 4 * t + 3], qq.w);
    }
}

// ---------------- shadow stats -> affine coef (a, c): bn(v) = a*v + c ----------------
__global__ void k_bn_coef(const float* __restrict__ stats_sh, const float* __restrict__ gamma,
                          const float* __restrict__ beta, float* __restrict__ coef) {
    int j = threadIdx.x;   // 64
    float s = 0.f, s2 = 0.f;
    for (int c = 0; c < NSHADOW; ++c) {
        s  += stats_sh[c * 128 + j];
        s2 += stats_sh[c * 128 + 64 + j];
    }
    float mu  = s * (1.0f / N_NODES);
    float var = s2 * (1.0f / N_NODES) - mu * mu;
    float rs  = rsqrtf(var + EPS);
    float a   = gamma[j] * rs;
    coef[j]      = a;
    coef[64 + j] = fmaf(-a, mu, beta[j]);
}

// ---------------- mean pool with fused BN+ReLU ----------------
__global__ void k_pool(const float* __restrict__ h, const float* __restrict__ coef,
                       float* __restrict__ pooled) {
    int t = threadIdx.x;
    int j = t & 63, rg = t >> 6;
    float a = coef[j], c = coef[64 + j];
    float s = 0.f;
    for (int n = blockIdx.x * 4 + rg; n < N_NODES; n += gridDim.x * 4)
        s += fmaxf(fmaf(a, h[n * HD + j], c), 0.f);
    __shared__ float ls[256];
    ls[t] = s;
    __syncthreads();
    if (t < 64)
        atomicAdd(&pooled[j], ls[t] + ls[t + 64] + ls[t + 128] + ls[t + 192]);
}

// ---------------- output ----------------
__global__ void k_out(const float* __restrict__ pooled, const float* __restrict__ Wout,
                      const float* __restrict__ bout, float* __restrict__ out) {
    int o = threadIdx.x;
    float acc = bout[o];
#pragma unroll
    for (int k = 0; k < HD; ++k)
        acc = fmaf(pooled[k] * (1.0f / N_NODES), Wout[k * HD + o], acc);
    out[o] = acc;
}

extern "C" void kernel_launch(void* const* d_in, const int* in_sizes, int n_in,
                              void* d_out, int out_size, void* d_ws, size_t ws_size,
                              hipStream_t stream) {
    const float* x        = (const float*)d_in[0];
    const int*   ei       = (const int*)  d_in[1];
    const float* W_embed  = (const float*)d_in[2];
    const float* b_embed  = (const float*)d_in[3];
    const float* conv_W   = (const float*)d_in[4];
    const float* conv_b   = (const float*)d_in[5];
    const float* bn_gamma = (const float*)d_in[6];
    const float* bn_beta  = (const float*)d_in[7];
    const float* W_out    = (const float*)d_in[8];
    const float* b_out    = (const float*)d_in[9];
    float* out = (float*)d_out;

    float* ws = (float*)d_ws;
    int*   deg       = (int*)ws;                          // N
    float* dinv      = ws + N_NODES;                      // N
    int*   row_start = (int*)(ws + 2 * N_NODES);          // N+1 (pad 8)
    float* small     = ws + 3 * N_NODES + 8;
    int*   bsum      = (int*)small;                       // 256
    int*   boff      = (int*)(small + 256);               // 256
    float* stats_sh  = small + 512;                       // NSHADOW*128 = 8192
    float* pooled    = small + 8704;                      // 64
    float* coef      = small + 8768;                      // 4*128 = 512
    int*   flag      = (int*)(small + 9280);              // 1 (pad 64)
    int*   csr_src   = (int*)(small + 9344);              // E
    float* bufA      = small + 9344 + N_EDGES;            // N*64 f32 (h / embed out)
    float* bufB      = bufA + N_NODES * HD;               // N*32 used as bf16x2 (xw)
    int*   rank      = (int*)bufB;                        // E ints (aliases bufB, pre-GEMM only)

    hipMemsetAsync(deg, 0, N_NODES * sizeof(int), stream);
    k_detect<<<1, 64, 0, stream>>>(ei, flag);
    k_deg_rank<<<(N_EDGES + 255) / 256, 256, 0, stream>>>(ei, flag, deg, rank);
    k_dinv<<<(N_NODES + 255) / 256, 256, 0, stream>>>(deg, dinv);
    k_scan1<<<SCAN_G, SCAN_B, 0, stream>>>(deg, bsum);
    k_scan2<<<1, 256, 0, stream>>>(bsum, boff, ((int*)(ws + 2 * N_NODES)) + N_NODES);
    k_scan3<<<SCAN_G, SCAN_B, 0, stream>>>(deg, boff, row_start);
    k_embed<<<(N_NODES + 3) / 4, 256, 0, stream>>>(x, W_embed, b_embed, bufA);
    k_bucket<<<(N_EDGES + 255) / 256, 256, 0, stream>>>(ei, flag, row_start, rank, csr_src);

    for (int l = 0; l < 4; ++l) {
        k_gemm128<<<(N_NODES + BM - 1) / BM, 256, 0, stream>>>(
            (const float4*)bufA, conv_W + l * HD * HD,
            l ? coef + (l - 1) * 128 : nullptr, dinv, (uint2*)bufB);
        hipMemsetAsync(stats_sh, 0, NSHADOW * 128 * sizeof(float), stream);
        k_gather_stats<<<(N_NODES + 15) / 16, 256, 0, stream>>>(
            (const uint2*)bufB, row_start, csr_src, dinv, conv_b + l * HD,
            (float4*)bufA, stats_sh);
        k_bn_coef<<<1, 64, 0, stream>>>(stats_sh, bn_gamma + l * HD, bn_beta + l * HD,
                                        coef + l * 128);
    }

    hipMemsetAsync(pooled, 0, 64 * sizeof(float), stream);
    k_pool<<<1024, 256, 0, stream>>>(bufA, coef + 3 * 128, pooled);
    k_out<<<1, 64, 0, stream>>>(pooled, W_out, b_out, out);
}

// Round 12
// 489.944 us; speedup vs baseline: 2.5922x; 1.1193x over previous
//
#include <hip/hip_runtime.h>

#define N_NODES 100000
#define N_EDGES 1600000
#define F_IN    32
#define HD      64
#define EPS     1e-5f
#define SCAN_B  512
#define SCAN_G  ((N_NODES + SCAN_B - 1) / SCAN_B)   // 196
#define NSHADOW 64

typedef __attribute__((ext_vector_type(8))) short short8v;
typedef __attribute__((ext_vector_type(4))) float f32x4;

// bf16 round-to-nearest-even pack/unpack
__device__ __forceinline__ unsigned bf16r(float f) {
    unsigned u = __float_as_uint(f);
    return (u + 0x7fffu + ((u >> 16) & 1u)) >> 16;
}
__device__ __forceinline__ unsigned pack2(float lo, float hi) {
    return bf16r(lo) | (bf16r(hi) << 16);
}
__device__ __forceinline__ float unlo(unsigned u) { return __uint_as_float(u << 16); }
__device__ __forceinline__ float unhi(unsigned u) { return __uint_as_float(u & 0xffff0000u); }

// ---------------- edge-index dtype probe ----------------
__global__ void k_detect(const int* __restrict__ ei, int* __restrict__ flag) {
    if (threadIdx.x == 0 && blockIdx.x == 0) {
        int all_zero = 1;
        for (int k = 0; k < 64; ++k)
            if (ei[2 * k + 1] != 0) { all_zero = 0; break; }
        *flag = all_zero;   // 1 -> int64 layout, 0 -> int32 layout
    }
}

__device__ __forceinline__ int load_src(const int* ei, int e, int is64) {
    return is64 ? ei[2 * e] : ei[e];
}
__device__ __forceinline__ int load_dst(const int* ei, int e, int is64) {
    return is64 ? ei[2 * (N_EDGES + e)] : ei[N_EDGES + e];
}

// ---------------- degree histogram + per-edge rank ----------------
__global__ void k_deg_rank(const int* __restrict__ ei, const int* __restrict__ flag,
                           int* __restrict__ deg, int* __restrict__ rank) {
    int e = blockIdx.x * blockDim.x + threadIdx.x;
    if (e >= N_EDGES) return;
    int is64 = *flag;
    rank[e] = atomicAdd(&deg[load_dst(ei, e, is64)], 1);
}

__global__ void k_dinv(const int* __restrict__ deg, float* __restrict__ dinv) {
    int n = blockIdx.x * blockDim.x + threadIdx.x;
    if (n >= N_NODES) return;
    dinv[n] = rsqrtf((float)deg[n] + 1.0f);
}

// ---------------- hierarchical scan ----------------
__global__ void k_scan1(const int* __restrict__ deg, int* __restrict__ bsum) {
    int t = threadIdx.x;
    int i = blockIdx.x * SCAN_B + t;
    __shared__ int ls[SCAN_B];
    ls[t] = (i < N_NODES) ? deg[i] : 0;
    __syncthreads();
    for (int off = SCAN_B / 2; off > 0; off >>= 1) {
        if (t < off) ls[t] += ls[t + off];
        __syncthreads();
    }
    if (t == 0) bsum[blockIdx.x] = ls[0];
}

__global__ void k_scan2(const int* __restrict__ bsum, int* __restrict__ boff,
                        int* __restrict__ row_start_last) {
    __shared__ int ls[256];
    int t = threadIdx.x;
    ls[t] = (t < SCAN_G) ? bsum[t] : 0;
    __syncthreads();
    for (int off = 1; off < 256; off <<= 1) {
        int u = (t >= off) ? ls[t - off] : 0;
        __syncthreads();
        ls[t] += u;
        __syncthreads();
    }
    boff[t] = (t == 0) ? 0 : ls[t - 1];
    if (t == 255) *row_start_last = ls[255];
}

__global__ void k_scan3(const int* __restrict__ deg, const int* __restrict__ boff,
                        int* __restrict__ row_start) {
    int t = threadIdx.x;
    int i = blockIdx.x * SCAN_B + t;
    int v = (i < N_NODES) ? deg[i] : 0;
    __shared__ int ls[SCAN_B];
    ls[t] = v;
    __syncthreads();
    for (int off = 1; off < SCAN_B; off <<= 1) {
        int u = (t >= off) ? ls[t - off] : 0;
        __syncthreads();
        ls[t] += u;
        __syncthreads();
    }
    if (i < N_NODES) row_start[i] = boff[blockIdx.x] + ls[t] - v;
}

// ---------------- bucket edges into CSR (atomic-free) ----------------
__global__ void k_bucket(const int* __restrict__ ei, const int* __restrict__ flag,
                         const int* __restrict__ row_start, const int* __restrict__ rank,
                         int* __restrict__ csr_src) {
    int e = blockIdx.x * blockDim.x + threadIdx.x;
    if (e >= N_EDGES) return;
    int is64 = *flag;
    int s = load_src(ei, e, is64);
    int d = load_dst(ei, e, is64);
    csr_src[row_start[d] + rank[e]] = s;
}

// ---------------- node embedding: hb = bf16(x @ W_embed + b) ----------------
__global__ void k_embed(const float* __restrict__ x, const float* __restrict__ W,
                        const float* __restrict__ b, unsigned* __restrict__ hb) {
    __shared__ float Ws[F_IN * HD];
    __shared__ float xs[4 * F_IN];
    int t = threadIdx.x;
    for (int i = t; i < F_IN * HD; i += 256) Ws[i] = W[i];
    if (t < 4 * F_IN) {
        int r = t >> 5, c = t & 31;
        int node = blockIdx.x * 4 + r;
        xs[t] = (node < N_NODES) ? x[node * F_IN + c] : 0.f;
    }
    __syncthreads();
    int r = t >> 6, j = t & 63;
    int node = blockIdx.x * 4 + r;
    float acc = b[j];
#pragma unroll
    for (int k = 0; k < F_IN; ++k)
        acc = fmaf(xs[r * F_IN + k], Ws[k * HD + j], acc);
    float other = __shfl_xor(acc, 1);
    if (node < N_NODES && (j & 1) == 0)
        hb[node * 32 + (j >> 1)] = pack2(acc, other);
}

// ---------------- MFMA GEMM: Cb[n] = bf16((relu(a*hb[n]+c) @ W) * dinv[n]) ----------------
// 4 waves x 16 rows = 64 rows/block. A from global bf16, B = W staged bf16-T in LDS.
__global__ void __launch_bounds__(256)
k_gemm_mfma(const unsigned* __restrict__ Ab, const float* __restrict__ W,
            const float* __restrict__ coef, const float* __restrict__ dinv,
            uint2* __restrict__ Cb) {
    __shared__ short Wt[64 * 72];          // Wt[j*72+k], bf16, ~9 KB
    __shared__ float Cs[4][16 * 66];       // per-wave C stage, ~16.9 KB
    int t = threadIdx.x;

    for (int i = t; i < HD * HD; i += 256) {
        int k = i >> 6, j = i & 63;
        Wt[j * 72 + k] = (short)bf16r(W[i]);
    }
    __syncthreads();

    int wid = t >> 6, lane = t & 63;
    int rlane = lane & 15, kb = lane >> 4;
    int base = blockIdx.x * 64 + wid * 16;
    int arow = base + rlane;
    if (arow > N_NODES - 1) arow = N_NODES - 1;   // clamp reads; writes guarded
    bool has_coef = (coef != nullptr);

    short8v afrag[2];
#pragma unroll
    for (int h = 0; h < 2; ++h) {
        uint4 p = *reinterpret_cast<const uint4*>(Ab + arow * 32 + h * 16 + kb * 4);
        union { uint4 u; short8v s; } cv;
        if (has_coef) {
            int k0 = h * 32 + kb * 8;
            float v0 = unlo(p.x), v1 = unhi(p.x), v2 = unlo(p.y), v3 = unhi(p.y);
            float v4 = unlo(p.z), v5 = unhi(p.z), v6 = unlo(p.w), v7 = unhi(p.w);
            v0 = fmaxf(fmaf(coef[k0 + 0], v0, coef[64 + k0 + 0]), 0.f);
            v1 = fmaxf(fmaf(coef[k0 + 1], v1, coef[64 + k0 + 1]), 0.f);
            v2 = fmaxf(fmaf(coef[k0 + 2], v2, coef[64 + k0 + 2]), 0.f);
            v3 = fmaxf(fmaf(coef[k0 + 3], v3, coef[64 + k0 + 3]), 0.f);
            v4 = fmaxf(fmaf(coef[k0 + 4], v4, coef[64 + k0 + 4]), 0.f);
            v5 = fmaxf(fmaf(coef[k0 + 5], v5, coef[64 + k0 + 5]), 0.f);
            v6 = fmaxf(fmaf(coef[k0 + 6], v6, coef[64 + k0 + 6]), 0.f);
            v7 = fmaxf(fmaf(coef[k0 + 7], v7, coef[64 + k0 + 7]), 0.f);
            cv.u.x = pack2(v0, v1); cv.u.y = pack2(v2, v3);
            cv.u.z = pack2(v4, v5); cv.u.w = pack2(v6, v7);
        } else {
            cv.u = p;
        }
        afrag[h] = cv.s;
    }

    f32x4 acc[4];
#pragma unroll
    for (int nt = 0; nt < 4; ++nt) acc[nt] = (f32x4){0.f, 0.f, 0.f, 0.f};

#pragma unroll
    for (int nt = 0; nt < 4; ++nt) {
        int col = nt * 16 + rlane;
#pragma unroll
        for (int h = 0; h < 2; ++h) {
            short8v b = *reinterpret_cast<const short8v*>(&Wt[col * 72 + h * 32 + kb * 8]);
            acc[nt] = __builtin_amdgcn_mfma_f32_16x16x32_bf16(afrag[h], b, acc[nt], 0, 0, 0);
        }
    }

    float dv[4];
#pragma unroll
    for (int r = 0; r < 4; ++r) {
        int g = base + kb * 4 + r;
        dv[r] = dinv[g > N_NODES - 1 ? N_NODES - 1 : g];
    }
#pragma unroll
    for (int nt = 0; nt < 4; ++nt) {
        int col = nt * 16 + rlane;
#pragma unroll
        for (int r = 0; r < 4; ++r)
            Cs[wid][(kb * 4 + r) * 66 + col] = acc[nt][r] * dv[r];
    }
    __syncthreads();

#pragma unroll
    for (int u = 0; u < 4; ++u) {
        int o = u * 64 + lane;          // 0..255 within wave tile
        int row = o >> 4, q = o & 15;
        int node = base - rlane + rlane; // keep base; node computed from block origin:
        node = blockIdx.x * 64 + wid * 16 + row;
        if (node < N_NODES) {
            const float* cp = &Cs[wid][row * 66 + q * 4];
            uint2 pq;
            pq.x = pack2(cp[0], cp[1]);
            pq.y = pack2(cp[2], cp[3]);
            Cb[node * 16 + q] = pq;
        }
    }
}

// ---------------- CSR gather (bf16 messages) + fused BN stats, bf16 h out ----------------
__global__ void __launch_bounds__(256)
k_gather_stats(const uint2* __restrict__ xwb, const int* __restrict__ row_start,
               const int* __restrict__ csr_src, const float* __restrict__ dinv,
               const float* __restrict__ cb, uint2* __restrict__ hb2,
               float* __restrict__ stats_sh) {
    int t = threadIdx.x;
    int q = t & 15;
    int r = t >> 4;
    int n = blockIdx.x * 16 + r;
    bool valid = (n < N_NODES);
    int beg = 0, end = 0;
    if (valid) { beg = row_start[n]; end = row_start[n + 1]; }
    float4 a0 = {0.f, 0.f, 0.f, 0.f}, a1 = {0.f, 0.f, 0.f, 0.f};
    if (valid) {
        uint2 p = xwb[n * 16 + q];
        a0.x = unlo(p.x); a0.y = unhi(p.x); a0.z = unlo(p.y); a0.w = unhi(p.y);
    }
    int e = beg;
    for (; e + 1 < end; e += 2) {
        int s0 = csr_src[e], s1 = csr_src[e + 1];
        uint2 p0 = xwb[s0 * 16 + q];
        uint2 p1 = xwb[s1 * 16 + q];
        a0.x += unlo(p0.x); a0.y += unhi(p0.x); a0.z += unlo(p0.y); a0.w += unhi(p0.y);
        a1.x += unlo(p1.x); a1.y += unhi(p1.x); a1.z += unlo(p1.y); a1.w += unhi(p1.y);
    }
    if (e < end) {
        int s0 = csr_src[e];
        uint2 p0 = xwb[s0 * 16 + q];
        a0.x += unlo(p0.x); a0.y += unhi(p0.x); a0.z += unlo(p0.y); a0.w += unhi(p0.y);
    }
    float dn = valid ? dinv[n] : 0.f;
    float4 h;
    h.x = fmaf(a0.x + a1.x, dn, cb[q * 4 + 0]);
    h.y = fmaf(a0.y + a1.y, dn, cb[q * 4 + 1]);
    h.z = fmaf(a0.z + a1.z, dn, cb[q * 4 + 2]);
    h.w = fmaf(a0.w + a1.w, dn, cb[q * 4 + 3]);
    if (valid) {
        uint2 o;
        o.x = pack2(h.x, h.y);
        o.y = pack2(h.z, h.w);
        hb2[n * 16 + q] = o;
    }

    // fused BN stats (sum, sumsq per column) in f32
    float4 hs = valid ? h : make_float4(0.f, 0.f, 0.f, 0.f);
    __shared__ float4 ls_s[256], ls_q[256];   // 8 KB
    ls_s[t] = hs;
    float4 hq; hq.x = hs.x * hs.x; hq.y = hs.y * hs.y; hq.z = hs.z * hs.z; hq.w = hs.w * hs.w;
    ls_q[t] = hq;
    __syncthreads();
    if (t < 16) {
        float4 ss = ls_s[t], qq = ls_q[t];
        for (int rr = 1; rr < 16; ++rr) {
            float4 u = ls_s[rr * 16 + t], v = ls_q[rr * 16 + t];
            ss.x += u.x; ss.y += u.y; ss.z += u.z; ss.w += u.w;
            qq.x += v.x; qq.y += v.y; qq.z += v.z; qq.w += v.w;
        }
        float* sh = stats_sh + (blockIdx.x & (NSHADOW - 1)) * 128;
        atomicAdd(&sh[4 * t + 0], ss.x);
        atomicAdd(&sh[4 * t + 1], ss.y);
        atomicAdd(&sh[4 * t + 2], ss.z);
        atomicAdd(&sh[4 * t + 3], ss.w);
        atomicAdd(&sh[64 + 4 * t + 0], qq.x);
        atomicAdd(&sh[64 + 4 * t + 1], qq.y);
        atomicAdd(&sh[64 + 4 * t + 2], qq.z);
        atomicAdd(&sh[64 + 4 * t + 3], qq.w);
    }
}

// ---------------- shadow stats -> affine coef (a, c): bn(v) = a*v + c ----------------
__global__ void k_bn_coef(const float* __restrict__ stats_sh, const float* __restrict__ gamma,
                          const float* __restrict__ beta, float* __restrict__ coef) {
    int j = threadIdx.x;   // 64
    float s = 0.f, s2 = 0.f;
    for (int c = 0; c < NSHADOW; ++c) {
        s  += stats_sh[c * 128 + j];
        s2 += stats_sh[c * 128 + 64 + j];
    }
    float mu  = s * (1.0f / N_NODES);
    float var = s2 * (1.0f / N_NODES) - mu * mu;
    float rs  = rsqrtf(var + EPS);
    float a   = gamma[j] * rs;
    coef[j]      = a;
    coef[64 + j] = fmaf(-a, mu, beta[j]);
}

// ---------------- mean pool with fused BN+ReLU (bf16 h in) ----------------
__global__ void k_pool(const unsigned* __restrict__ hb, const float* __restrict__ coef,
                       float* __restrict__ pooled) {
    int t = threadIdx.x;
    int j = t & 63, rg = t >> 6;
    float a = coef[j], c = coef[64 + j];
    float s = 0.f;
    for (int n = blockIdx.x * 4 + rg; n < N_NODES; n += gridDim.x * 4) {
        unsigned p = hb[n * 32 + (j >> 1)];
        float v = (j & 1) ? unhi(p) : unlo(p);
        s += fmaxf(fmaf(a, v, c), 0.f);
    }
    __shared__ float ls[256];
    ls[t] = s;
    __syncthreads();
    if (t < 64)
        atomicAdd(&pooled[j], ls[t] + ls[t + 64] + ls[t + 128] + ls[t + 192]);
}

// ---------------- output ----------------
__global__ void k_out(const float* __restrict__ pooled, const float* __restrict__ Wout,
                      const float* __restrict__ bout, float* __restrict__ out) {
    int o = threadIdx.x;
    float acc = bout[o];
#pragma unroll
    for (int k = 0; k < HD; ++k)
        acc = fmaf(pooled[k] * (1.0f / N_NODES), Wout[k * HD + o], acc);
    out[o] = acc;
}

extern "C" void kernel_launch(void* const* d_in, const int* in_sizes, int n_in,
                              void* d_out, int out_size, void* d_ws, size_t ws_size,
                              hipStream_t stream) {
    const float* x        = (const float*)d_in[0];
    const int*   ei       = (const int*)  d_in[1];
    const float* W_embed  = (const float*)d_in[2];
    const float* b_embed  = (const float*)d_in[3];
    const float* conv_W   = (const float*)d_in[4];
    const float* conv_b   = (const float*)d_in[5];
    const float* bn_gamma = (const float*)d_in[6];
    const float* bn_beta  = (const float*)d_in[7];
    const float* W_out    = (const float*)d_in[8];
    const float* b_out    = (const float*)d_in[9];
    float* out = (float*)d_out;

    float* ws = (float*)d_ws;
    int*   deg       = (int*)ws;                          // N
    float* dinv      = ws + N_NODES;                      // N
    int*   row_start = (int*)(ws + 2 * N_NODES);          // N+1 (pad 8)
    float* small     = ws + 3 * N_NODES + 8;
    int*   bsum      = (int*)small;                       // 256
    int*   boff      = (int*)(small + 256);               // 256
    float* stats_sh  = small + 512;                       // NSHADOW*128 = 8192
    float* pooled    = small + 8704;                      // 64
    float* coef      = small + 8768;                      // 4*128 = 512
    int*   flag      = (int*)(small + 9280);              // 1 (pad 64)
    int*   csr_src   = (int*)(small + 9344);              // E
    float* bufA      = small + 9344 + N_EDGES;            // N*32 uints (bf16 h)
    float* bufB      = bufA + N_NODES * 32;               // N*32 uints (bf16 xw)
    int*   rank      = (int*)bufB;                        // E ints (aliases bufB, pre-GEMM only)

    hipMemsetAsync(deg, 0, N_NODES * sizeof(int), stream);
    k_detect<<<1, 64, 0, stream>>>(ei, flag);
    k_deg_rank<<<(N_EDGES + 255) / 256, 256, 0, stream>>>(ei, flag, deg, rank);
    k_dinv<<<(N_NODES + 255) / 256, 256, 0, stream>>>(deg, dinv);
    k_scan1<<<SCAN_G, SCAN_B, 0, stream>>>(deg, bsum);
    k_scan2<<<1, 256, 0, stream>>>(bsum, boff, ((int*)(ws + 2 * N_NODES)) + N_NODES);
    k_scan3<<<SCAN_G, SCAN_B, 0, stream>>>(deg, boff, row_start);
    k_embed<<<(N_NODES + 3) / 4, 256, 0, stream>>>(x, W_embed, b_embed, (unsigned*)bufA);
    k_bucket<<<(N_EDGES + 255) / 256, 256, 0, stream>>>(ei, flag, row_start, rank, csr_src);

    for (int l = 0; l < 4; ++l) {
        k_gemm_mfma<<<(N_NODES + 63) / 64, 256, 0, stream>>>(
            (const unsigned*)bufA, conv_W + l * HD * HD,
            l ? coef + (l - 1) * 128 : nullptr, dinv, (uint2*)bufB);
        hipMemsetAsync(stats_sh, 0, NSHADOW * 128 * sizeof(float), stream);
        k_gather_stats<<<(N_NODES + 15) / 16, 256, 0, stream>>>(
            (const uint2*)bufB, row_start, csr_src, dinv, conv_b + l * HD,
            (uint2*)bufA, stats_sh);
        k_bn_coef<<<1, 64, 0, stream>>>(stats_sh, bn_gamma + l * HD, bn_beta + l * HD,
                                        coef + l * 128);
    }

    hipMemsetAsync(pooled, 0, 64 * sizeof(float), stream);
    k_pool<<<1024, 256, 0, stream>>>((const unsigned*)bufA, coef + 3 * 128, pooled);
    k_out<<<1, 64, 0, stream>>>(pooled, W_out, b_out, out);
}

// Round 13
// 424.281 us; speedup vs baseline: 2.9934x; 1.1548x over previous
//
#include <hip/hip_runtime.h>

#define N_NODES 100000
#define N_EDGES 1600000
#define F_IN    32
#define HD      64
#define EPS     1e-5f
#define SCAN_B  512
#define SCAN_G  ((N_NODES + SCAN_B - 1) / SCAN_B)   // 196
#define NSHADOW 64

typedef __attribute__((ext_vector_type(8))) short short8v;
typedef __attribute__((ext_vector_type(4))) float f32x4;
typedef __attribute__((ext_vector_type(2))) float f32x2;

// bf16 round-to-nearest-even pack/unpack
__device__ __forceinline__ unsigned bf16r(float f) {
    unsigned u = __float_as_uint(f);
    return (u + 0x7fffu + ((u >> 16) & 1u)) >> 16;
}
__device__ __forceinline__ unsigned pack2(float lo, float hi) {
    return bf16r(lo) | (bf16r(hi) << 16);
}
__device__ __forceinline__ float unlo(unsigned u) { return __uint_as_float(u << 16); }
__device__ __forceinline__ float unhi(unsigned u) { return __uint_as_float(u & 0xffff0000u); }

// fp8 e4m3 (OCP) pack/unpack via gfx950 HW converts
__device__ __forceinline__ unsigned pack_fp8x4(float a, float b, float c, float d) {
    int v = __builtin_amdgcn_cvt_pk_fp8_f32(a, b, 0, false);
    v = __builtin_amdgcn_cvt_pk_fp8_f32(c, d, v, true);
    return (unsigned)v;
}

// ---------------- edge-index dtype probe ----------------
__global__ void k_detect(const int* __restrict__ ei, int* __restrict__ flag) {
    if (threadIdx.x == 0 && blockIdx.x == 0) {
        int all_zero = 1;
        for (int k = 0; k < 64; ++k)
            if (ei[2 * k + 1] != 0) { all_zero = 0; break; }
        *flag = all_zero;   // 1 -> int64 layout, 0 -> int32 layout
    }
}

__device__ __forceinline__ int load_src(const int* ei, int e, int is64) {
    return is64 ? ei[2 * e] : ei[e];
}
__device__ __forceinline__ int load_dst(const int* ei, int e, int is64) {
    return is64 ? ei[2 * (N_EDGES + e)] : ei[N_EDGES + e];
}

// ---------------- degree histogram + per-edge rank ----------------
__global__ void k_deg_rank(const int* __restrict__ ei, const int* __restrict__ flag,
                           int* __restrict__ deg, int* __restrict__ rank) {
    int e = blockIdx.x * blockDim.x + threadIdx.x;
    if (e >= N_EDGES) return;
    int is64 = *flag;
    rank[e] = atomicAdd(&deg[load_dst(ei, e, is64)], 1);
}

__global__ void k_dinv(const int* __restrict__ deg, float* __restrict__ dinv) {
    int n = blockIdx.x * blockDim.x + threadIdx.x;
    if (n >= N_NODES) return;
    dinv[n] = rsqrtf((float)deg[n] + 1.0f);
}

// ---------------- hierarchical scan ----------------
__global__ void k_scan1(const int* __restrict__ deg, int* __restrict__ bsum) {
    int t = threadIdx.x;
    int i = blockIdx.x * SCAN_B + t;
    __shared__ int ls[SCAN_B];
    ls[t] = (i < N_NODES) ? deg[i] : 0;
    __syncthreads();
    for (int off = SCAN_B / 2; off > 0; off >>= 1) {
        if (t < off) ls[t] += ls[t + off];
        __syncthreads();
    }
    if (t == 0) bsum[blockIdx.x] = ls[0];
}

__global__ void k_scan2(const int* __restrict__ bsum, int* __restrict__ boff,
                        int* __restrict__ row_start_last) {
    __shared__ int ls[256];
    int t = threadIdx.x;
    ls[t] = (t < SCAN_G) ? bsum[t] : 0;
    __syncthreads();
    for (int off = 1; off < 256; off <<= 1) {
        int u = (t >= off) ? ls[t - off] : 0;
        __syncthreads();
        ls[t] += u;
        __syncthreads();
    }
    boff[t] = (t == 0) ? 0 : ls[t - 1];
    if (t == 255) *row_start_last = ls[255];
}

__global__ void k_scan3(const int* __restrict__ deg, const int* __restrict__ boff,
                        int* __restrict__ row_start) {
    int t = threadIdx.x;
    int i = blockIdx.x * SCAN_B + t;
    int v = (i < N_NODES) ? deg[i] : 0;
    __shared__ int ls[SCAN_B];
    ls[t] = v;
    __syncthreads();
    for (int off = 1; off < SCAN_B; off <<= 1) {
        int u = (t >= off) ? ls[t - off] : 0;
        __syncthreads();
        ls[t] += u;
        __syncthreads();
    }
    if (i < N_NODES) row_start[i] = boff[blockIdx.x] + ls[t] - v;
}

// ---------------- bucket edges into CSR (atomic-free) ----------------
__global__ void k_bucket(const int* __restrict__ ei, const int* __restrict__ flag,
                         const int* __restrict__ row_start, const int* __restrict__ rank,
                         int* __restrict__ csr_src) {
    int e = blockIdx.x * blockDim.x + threadIdx.x;
    if (e >= N_EDGES) return;
    int is64 = *flag;
    int s = load_src(ei, e, is64);
    int d = load_dst(ei, e, is64);
    csr_src[row_start[d] + rank[e]] = s;
}

// ---------------- node embedding: hb = bf16(x @ W_embed + b) ----------------
__global__ void k_embed(const float* __restrict__ x, const float* __restrict__ W,
                        const float* __restrict__ b, unsigned* __restrict__ hb) {
    __shared__ float Ws[F_IN * HD];
    __shared__ float xs[4 * F_IN];
    int t = threadIdx.x;
    for (int i = t; i < F_IN * HD; i += 256) Ws[i] = W[i];
    if (t < 4 * F_IN) {
        int r = t >> 5, c = t & 31;
        int node = blockIdx.x * 4 + r;
        xs[t] = (node < N_NODES) ? x[node * F_IN + c] : 0.f;
    }
    __syncthreads();
    int r = t >> 6, j = t & 63;
    int node = blockIdx.x * 4 + r;
    float acc = b[j];
#pragma unroll
    for (int k = 0; k < F_IN; ++k)
        acc = fmaf(xs[r * F_IN + k], Ws[k * HD + j], acc);
    float other = __shfl_xor(acc, 1);
    if (node < N_NODES && (j & 1) == 0)
        hb[node * 32 + (j >> 1)] = pack2(acc, other);
}

// ---------------- MFMA GEMM: Cf8[n] = fp8((relu(a*hb[n]+c) @ W) * dinv[n]) ----------------
// 4 waves x 16 rows = 64 rows/block. A from global bf16, B = W staged bf16-T in LDS.
__global__ void __launch_bounds__(256)
k_gemm_mfma(const unsigned* __restrict__ Ab, const float* __restrict__ W,
            const float* __restrict__ coef, const float* __restrict__ dinv,
            unsigned* __restrict__ Cf8) {
    __shared__ short Wt[64 * 72];          // Wt[j*72+k], bf16, ~9 KB
    __shared__ float Cs[4][16 * 66];       // per-wave C stage, ~16.9 KB
    int t = threadIdx.x;

    for (int i = t; i < HD * HD; i += 256) {
        int k = i >> 6, j = i & 63;
        Wt[j * 72 + k] = (short)bf16r(W[i]);
    }
    __syncthreads();

    int wid = t >> 6, lane = t & 63;
    int rlane = lane & 15, kb = lane >> 4;
    int base = blockIdx.x * 64 + wid * 16;
    int arow = base + rlane;
    if (arow > N_NODES - 1) arow = N_NODES - 1;   // clamp reads; writes guarded
    bool has_coef = (coef != nullptr);

    short8v afrag[2];
#pragma unroll
    for (int h = 0; h < 2; ++h) {
        uint4 p = *reinterpret_cast<const uint4*>(Ab + arow * 32 + h * 16 + kb * 4);
        union { uint4 u; short8v s; } cv;
        if (has_coef) {
            int k0 = h * 32 + kb * 8;
            float v0 = unlo(p.x), v1 = unhi(p.x), v2 = unlo(p.y), v3 = unhi(p.y);
            float v4 = unlo(p.z), v5 = unhi(p.z), v6 = unlo(p.w), v7 = unhi(p.w);
            v0 = fmaxf(fmaf(coef[k0 + 0], v0, coef[64 + k0 + 0]), 0.f);
            v1 = fmaxf(fmaf(coef[k0 + 1], v1, coef[64 + k0 + 1]), 0.f);
            v2 = fmaxf(fmaf(coef[k0 + 2], v2, coef[64 + k0 + 2]), 0.f);
            v3 = fmaxf(fmaf(coef[k0 + 3], v3, coef[64 + k0 + 3]), 0.f);
            v4 = fmaxf(fmaf(coef[k0 + 4], v4, coef[64 + k0 + 4]), 0.f);
            v5 = fmaxf(fmaf(coef[k0 + 5], v5, coef[64 + k0 + 5]), 0.f);
            v6 = fmaxf(fmaf(coef[k0 + 6], v6, coef[64 + k0 + 6]), 0.f);
            v7 = fmaxf(fmaf(coef[k0 + 7], v7, coef[64 + k0 + 7]), 0.f);
            cv.u.x = pack2(v0, v1); cv.u.y = pack2(v2, v3);
            cv.u.z = pack2(v4, v5); cv.u.w = pack2(v6, v7);
        } else {
            cv.u = p;
        }
        afrag[h] = cv.s;
    }

    f32x4 acc[4];
#pragma unroll
    for (int nt = 0; nt < 4; ++nt) acc[nt] = (f32x4){0.f, 0.f, 0.f, 0.f};

#pragma unroll
    for (int nt = 0; nt < 4; ++nt) {
        int col = nt * 16 + rlane;
#pragma unroll
        for (int h = 0; h < 2; ++h) {
            short8v b = *reinterpret_cast<const short8v*>(&Wt[col * 72 + h * 32 + kb * 8]);
            acc[nt] = __builtin_amdgcn_mfma_f32_16x16x32_bf16(afrag[h], b, acc[nt], 0, 0, 0);
        }
    }

    float dv[4];
#pragma unroll
    for (int r = 0; r < 4; ++r) {
        int g = base + kb * 4 + r;
        dv[r] = dinv[g > N_NODES - 1 ? N_NODES - 1 : g];
    }
#pragma unroll
    for (int nt = 0; nt < 4; ++nt) {
        int col = nt * 16 + rlane;
#pragma unroll
        for (int r = 0; r < 4; ++r)
            Cs[wid][(kb * 4 + r) * 66 + col] = acc[nt][r] * dv[r];
    }
    __syncthreads();

#pragma unroll
    for (int u = 0; u < 4; ++u) {
        int o = u * 64 + lane;          // 0..255 within wave tile
        int row = o >> 4, q = o & 15;   // q: uint slot (4 cols)
        int node = blockIdx.x * 64 + wid * 16 + row;
        if (node < N_NODES) {
            const float* cp = &Cs[wid][row * 66 + q * 4];
            Cf8[node * 16 + q] = pack_fp8x4(cp[0], cp[1], cp[2], cp[3]);
        }
    }
}

// ---------------- CSR gather (fp8 messages) + fused BN stats, bf16 h out ----------------
// 16 threads/node; thread q owns cols 4q..4q+3 (one uint = 4 fp8 per row).
__global__ void __launch_bounds__(256)
k_gather_stats(const unsigned* __restrict__ xwf8, const int* __restrict__ row_start,
               const int* __restrict__ csr_src, const float* __restrict__ dinv,
               const float* __restrict__ cb, uint2* __restrict__ hb2,
               float* __restrict__ stats_sh) {
    int t = threadIdx.x;
    int q = t & 15;
    int r = t >> 4;
    int n = blockIdx.x * 16 + r;
    bool valid = (n < N_NODES);
    int beg = 0, end = 0;
    if (valid) { beg = row_start[n]; end = row_start[n + 1]; }
    float4 a0 = {0.f, 0.f, 0.f, 0.f}, a1 = {0.f, 0.f, 0.f, 0.f};
    if (valid) {
        unsigned p = xwf8[n * 16 + q];
        f32x2 lo = __builtin_amdgcn_cvt_pk_f32_fp8((int)p, false);
        f32x2 hi = __builtin_amdgcn_cvt_pk_f32_fp8((int)p, true);
        a0.x = lo[0]; a0.y = lo[1]; a0.z = hi[0]; a0.w = hi[1];
    }
    int e = beg;
    for (; e + 1 < end; e += 2) {
        int s0 = csr_src[e], s1 = csr_src[e + 1];
        unsigned p0 = xwf8[s0 * 16 + q];
        unsigned p1 = xwf8[s1 * 16 + q];
        f32x2 l0 = __builtin_amdgcn_cvt_pk_f32_fp8((int)p0, false);
        f32x2 h0 = __builtin_amdgcn_cvt_pk_f32_fp8((int)p0, true);
        f32x2 l1 = __builtin_amdgcn_cvt_pk_f32_fp8((int)p1, false);
        f32x2 h1 = __builtin_amdgcn_cvt_pk_f32_fp8((int)p1, true);
        a0.x += l0[0]; a0.y += l0[1]; a0.z += h0[0]; a0.w += h0[1];
        a1.x += l1[0]; a1.y += l1[1]; a1.z += h1[0]; a1.w += h1[1];
    }
    if (e < end) {
        int s0 = csr_src[e];
        unsigned p0 = xwf8[s0 * 16 + q];
        f32x2 l0 = __builtin_amdgcn_cvt_pk_f32_fp8((int)p0, false);
        f32x2 h0 = __builtin_amdgcn_cvt_pk_f32_fp8((int)p0, true);
        a0.x += l0[0]; a0.y += l0[1]; a0.z += h0[0]; a0.w += h0[1];
    }
    float dn = valid ? dinv[n] : 0.f;
    float4 h;
    h.x = fmaf(a0.x + a1.x, dn, cb[q * 4 + 0]);
    h.y = fmaf(a0.y + a1.y, dn, cb[q * 4 + 1]);
    h.z = fmaf(a0.z + a1.z, dn, cb[q * 4 + 2]);
    h.w = fmaf(a0.w + a1.w, dn, cb[q * 4 + 3]);
    if (valid) {
        uint2 o;
        o.x = pack2(h.x, h.y);
        o.y = pack2(h.z, h.w);
        hb2[n * 16 + q] = o;
    }

    // fused BN stats (sum, sumsq per column) in f32
    float4 hs = valid ? h : make_float4(0.f, 0.f, 0.f, 0.f);
    __shared__ float4 ls_s[256], ls_q[256];   // 8 KB
    ls_s[t] = hs;
    float4 hq; hq.x = hs.x * hs.x; hq.y = hs.y * hs.y; hq.z = hs.z * hs.z; hq.w = hs.w * hs.w;
    ls_q[t] = hq;
    __syncthreads();
    if (t < 16) {
        float4 ss = ls_s[t], qq = ls_q[t];
        for (int rr = 1; rr < 16; ++rr) {
            float4 u = ls_s[rr * 16 + t], v = ls_q[rr * 16 + t];
            ss.x += u.x; ss.y += u.y; ss.z += u.z; ss.w += u.w;
            qq.x += v.x; qq.y += v.y; qq.z += v.z; qq.w += v.w;
        }
        float* sh = stats_sh + (blockIdx.x & (NSHADOW - 1)) * 128;
        atomicAdd(&sh[4 * t + 0], ss.x);
        atomicAdd(&sh[4 * t + 1], ss.y);
        atomicAdd(&sh[4 * t + 2], ss.z);
        atomicAdd(&sh[4 * t + 3], ss.w);
        atomicAdd(&sh[64 + 4 * t + 0], qq.x);
        atomicAdd(&sh[64 + 4 * t + 1], qq.y);
        atomicAdd(&sh[64 + 4 * t + 2], qq.z);
        atomicAdd(&sh[64 + 4 * t + 3], qq.w);
    }
}

// ---------------- shadow stats -> affine coef (a, c): bn(v) = a*v + c ----------------
__global__ void k_bn_coef(const float* __restrict__ stats_sh, const float* __restrict__ gamma,
                          const float* __restrict__ beta, float* __restrict__ coef) {
    int j = threadIdx.x;   // 64
    float s = 0.f, s2 = 0.f;
    for (int c = 0; c < NSHADOW; ++c) {
        s  += stats_sh[c * 128 + j];
        s2 += stats_sh[c * 128 + 64 + j];
    }
    float mu  = s * (1.0f / N_NODES);
    float var = s2 * (1.0f / N_NODES) - mu * mu;
    float rs  = rsqrtf(var + EPS);
    float a   = gamma[j] * rs;
    coef[j]      = a;
    coef[64 + j] = fmaf(-a, mu, beta[j]);
}

// ---------------- mean pool with fused BN+ReLU (bf16 h in) ----------------
__global__ void k_pool(const unsigned* __restrict__ hb, const float* __restrict__ coef,
                       float* __restrict__ pooled) {
    int t = threadIdx.x;
    int j = t & 63, rg = t >> 6;
    float a = coef[j], c = coef[64 + j];
    float s = 0.f;
    for (int n = blockIdx.x * 4 + rg; n < N_NODES; n += gridDim.x * 4) {
        unsigned p = hb[n * 32 + (j >> 1)];
        float v = (j & 1) ? unhi(p) : unlo(p);
        s += fmaxf(fmaf(a, v, c), 0.f);
    }
    __shared__ float ls[256];
    ls[t] = s;
    __syncthreads();
    if (t < 64)
        atomicAdd(&pooled[j], ls[t] + ls[t + 64] + ls[t + 128] + ls[t + 192]);
}

// ---------------- output ----------------
__global__ void k_out(const float* __restrict__ pooled, const float* __restrict__ Wout,
                      const float* __restrict__ bout, float* __restrict__ out) {
    int o = threadIdx.x;
    float acc = bout[o];
#pragma unroll
    for (int k = 0; k < HD; ++k)
        acc = fmaf(pooled[k] * (1.0f / N_NODES), Wout[k * HD + o], acc);
    out[o] = acc;
}

extern "C" void kernel_launch(void* const* d_in, const int* in_sizes, int n_in,
                              void* d_out, int out_size, void* d_ws, size_t ws_size,
                              hipStream_t stream) {
    const float* x        = (const float*)d_in[0];
    const int*   ei       = (const int*)  d_in[1];
    const float* W_embed  = (const float*)d_in[2];
    const float* b_embed  = (const float*)d_in[3];
    const float* conv_W   = (const float*)d_in[4];
    const float* conv_b   = (const float*)d_in[5];
    const float* bn_gamma = (const float*)d_in[6];
    const float* bn_beta  = (const float*)d_in[7];
    const float* W_out    = (const float*)d_in[8];
    const float* b_out    = (const float*)d_in[9];
    float* out = (float*)d_out;

    float* ws = (float*)d_ws;
    int*   deg       = (int*)ws;                          // N
    float* dinv      = ws + N_NODES;                      // N
    int*   row_start = (int*)(ws + 2 * N_NODES);          // N+1 (pad 8)
    float* small     = ws + 3 * N_NODES + 8;
    int*   bsum      = (int*)small;                       // 256
    int*   boff      = (int*)(small + 256);               // 256
    float* stats_sh  = small + 512;                       // NSHADOW*128 = 8192
    float* pooled    = small + 8704;                      // 64
    float* coef      = small + 8768;                      // 4*128 = 512
    int*   flag      = (int*)(small + 9280);              // 1 (pad 64)
    int*   csr_src   = (int*)(small + 9344);              // E
    float* bufA      = small + 9344 + N_EDGES;            // N*32 uints (bf16 h)
    float* bufB      = bufA + N_NODES * 32;               // N*16 uints (fp8 xw)
    int*   rank      = (int*)bufB;                        // E ints = 6.4MB (aliases bufB, pre-GEMM only)

    hipMemsetAsync(deg, 0, N_NODES * sizeof(int), stream);
    k_detect<<<1, 64, 0, stream>>>(ei, flag);
    k_deg_rank<<<(N_EDGES + 255) / 256, 256, 0, stream>>>(ei, flag, deg, rank);
    k_dinv<<<(N_NODES + 255) / 256, 256, 0, stream>>>(deg, dinv);
    k_scan1<<<SCAN_G, SCAN_B, 0, stream>>>(deg, bsum);
    k_scan2<<<1, 256, 0, stream>>>(bsum, boff, ((int*)(ws + 2 * N_NODES)) + N_NODES);
    k_scan3<<<SCAN_G, SCAN_B, 0, stream>>>(deg, boff, row_start);
    k_embed<<<(N_NODES + 3) / 4, 256, 0, stream>>>(x, W_embed, b_embed, (unsigned*)bufA);
    k_bucket<<<(N_EDGES + 255) / 256, 256, 0, stream>>>(ei, flag, row_start, rank, csr_src);

    for (int l = 0; l < 4; ++l) {
        k_gemm_mfma<<<(N_NODES + 63) / 64, 256, 0, stream>>>(
            (const unsigned*)bufA, conv_W + l * HD * HD,
            l ? coef + (l - 1) * 128 : nullptr, dinv, (unsigned*)bufB);
        hipMemsetAsync(stats_sh, 0, NSHADOW * 128 * sizeof(float), stream);
        k_gather_stats<<<(N_NODES + 15) / 16, 256, 0, stream>>>(
            (const unsigned*)bufB, row_start, csr_src, dinv, conv_b + l * HD,
            (uint2*)bufA, stats_sh);
        k_bn_coef<<<1, 64, 0, stream>>>(stats_sh, bn_gamma + l * HD, bn_beta + l * HD,
                                        coef + l * 128);
    }

    hipMemsetAsync(pooled, 0, 64 * sizeof(float), stream);
    k_pool<<<1024, 256, 0, stream>>>((const unsigned*)bufA, coef + 3 * 128, pooled);
    k_out<<<1, 64, 0, stream>>>(pooled, W_out, b_out, out);
}

// Round 16
// 387.104 us; speedup vs baseline: 3.2808x; 1.0960x over previous
//
#include <hip/hip_runtime.h>

#define N_NODES 100000
#define N_EDGES 1600000
#define F_IN    32
#define HD      64
#define EPS     1e-5f
#define SCAN_B  512
#define SCAN_G  ((N_NODES + SCAN_B - 1) / SCAN_B)   // 196
#define NSHADOW 64
#define NP      196      // partitions (512 nodes each)
#define PWS     9        // partition width shift
#define NB1     250      // blocks in pass1/2
#define EPB     6400     // edges per block (250*6400 = E exactly)

typedef __attribute__((ext_vector_type(8))) short short8v;
typedef __attribute__((ext_vector_type(4))) float f32x4;
typedef __attribute__((ext_vector_type(2))) float f32x2;

// bf16 round-to-nearest-even pack/unpack
__device__ __forceinline__ unsigned bf16r(float f) {
    unsigned u = __float_as_uint(f);
    return (u + 0x7fffu + ((u >> 16) & 1u)) >> 16;
}
__device__ __forceinline__ unsigned pack2(float lo, float hi) {
    return bf16r(lo) | (bf16r(hi) << 16);
}
__device__ __forceinline__ float unlo(unsigned u) { return __uint_as_float(u << 16); }
__device__ __forceinline__ float unhi(unsigned u) { return __uint_as_float(u & 0xffff0000u); }

// fp8 e4m3 (OCP) pack via gfx950 HW converts
__device__ __forceinline__ unsigned pack_fp8x4(float a, float b, float c, float d) {
    int v = __builtin_amdgcn_cvt_pk_fp8_f32(a, b, 0, false);
    v = __builtin_amdgcn_cvt_pk_fp8_f32(c, d, v, true);
    return (unsigned)v;
}

// ---------------- edge-index dtype probe ----------------
__global__ void k_detect(const int* __restrict__ ei, int* __restrict__ flag) {
    if (threadIdx.x == 0 && blockIdx.x == 0) {
        int all_zero = 1;
        for (int k = 0; k < 64; ++k)
            if (ei[2 * k + 1] != 0) { all_zero = 0; break; }
        *flag = all_zero;   // 1 -> int64 layout, 0 -> int32 layout
    }
}

__device__ __forceinline__ int load_src(const int* ei, int e, int is64) {
    return is64 ? ei[2 * e] : ei[e];
}
__device__ __forceinline__ int load_dst(const int* ei, int e, int is64) {
    return is64 ? ei[2 * (N_EDGES + e)] : ei[N_EDGES + e];
}

// ---------------- CSR build pass 1: per-(block,partition) histogram ----------------
__global__ void __launch_bounds__(256)
k_p1_hist(const int* __restrict__ ei, const int* __restrict__ flag, int* __restrict__ hcnt) {
    __shared__ int hist[NP];
    int t = threadIdx.x, b = blockIdx.x;
    if (t < NP) hist[t] = 0;
    __syncthreads();
    int is64 = *flag;
#pragma unroll 5
    for (int i = 0; i < 25; ++i) {
        int e = b * EPB + i * 256 + t;
        int d = load_dst(ei, e, is64);
        atomicAdd(&hist[d >> PWS], 1);
    }
    __syncthreads();
    if (t < NP) hcnt[t * NB1 + b] = hist[t];
}

// ---------------- pass 2 scan: per-partition exclusive scan over blocks ----------------
__global__ void k_p2scan(const int* __restrict__ hcnt, int* __restrict__ off_bp,
                         int* __restrict__ ptotal) {
    __shared__ int ls[256];
    int t = threadIdx.x, p = blockIdx.x;
    int v = (t < NB1) ? hcnt[p * NB1 + t] : 0;
    ls[t] = v;
    __syncthreads();
    for (int off = 1; off < 256; off <<= 1) {
        int u = (t >= off) ? ls[t - off] : 0;
        __syncthreads();
        ls[t] += u;
        __syncthreads();
    }
    if (t < NB1) off_bp[p * NB1 + t] = ls[t] - v;
    if (t == 255) ptotal[p] = ls[255];
}

// ---------------- scan partition totals -> pbase ----------------
__global__ void k_p3scan(const int* __restrict__ ptotal, int* __restrict__ pbase) {
    __shared__ int ls[256];
    int t = threadIdx.x;
    int v = (t < NP) ? ptotal[t] : 0;
    ls[t] = v;
    __syncthreads();
    for (int off = 1; off < 256; off <<= 1) {
        int u = (t >= off) ? ls[t - off] : 0;
        __syncthreads();
        ls[t] += u;
        __syncthreads();
    }
    if (t < NP) pbase[t] = ls[t] - v;
}

// ---------------- pass 2: scatter edge records into partition buffer ----------------
__global__ void __launch_bounds__(256)
k_p2_scatter(const int* __restrict__ ei, const int* __restrict__ flag,
             const int* __restrict__ off_bp, const int* __restrict__ pbase,
             uint2* __restrict__ part_buf) {
    __shared__ int cursor[NP];
    int t = threadIdx.x, b = blockIdx.x;
    if (t < NP) cursor[t] = pbase[t] + off_bp[t * NB1 + b];
    __syncthreads();
    int is64 = *flag;
#pragma unroll 5
    for (int i = 0; i < 25; ++i) {
        int e = b * EPB + i * 256 + t;
        int s = load_src(ei, e, is64);
        int d = load_dst(ei, e, is64);
        int slot = atomicAdd(&cursor[d >> PWS], 1);
        part_buf[slot] = make_uint2((unsigned)s, (unsigned)d);
    }
}

// ---------------- pass 3a: per-partition degree histogram ----------------
__global__ void __launch_bounds__(256)
k_p3a_deg(const uint2* __restrict__ part_buf, const int* __restrict__ pbase,
          const int* __restrict__ ptotal, int* __restrict__ deg) {
    __shared__ int hist[512];
    int t = threadIdx.x, p = blockIdx.x;
    hist[t] = 0; hist[t + 256] = 0;
    __syncthreads();
    int beg = pbase[p], cnt = ptotal[p];
    for (int r = t; r < cnt; r += 256)
        atomicAdd(&hist[part_buf[beg + r].y & 511], 1);
    __syncthreads();
    int n0 = (p << PWS) + t;
    if (n0 < N_NODES) deg[n0] = hist[t];
    if (n0 + 256 < N_NODES) deg[n0 + 256] = hist[t + 256];
}

// ---------------- pass 3b: place src into CSR via LDS cursors ----------------
__global__ void __launch_bounds__(256)
k_p3b_csr(const uint2* __restrict__ part_buf, const int* __restrict__ pbase,
          const int* __restrict__ ptotal, const int* __restrict__ row_start,
          int* __restrict__ csr_src) {
    __shared__ int cur[512];
    int t = threadIdx.x, p = blockIdx.x;
    int n0 = (p << PWS) + t;
    cur[t]       = (n0 < N_NODES)       ? row_start[n0]       : 0;
    cur[t + 256] = (n0 + 256 < N_NODES) ? row_start[n0 + 256] : 0;
    __syncthreads();
    int beg = pbase[p], cnt = ptotal[p];
    for (int r = t; r < cnt; r += 256) {
        uint2 rec = part_buf[beg + r];
        int slot = atomicAdd(&cur[rec.y & 511], 1);
        csr_src[slot] = (int)rec.x;
    }
}

__global__ void k_dinv(const int* __restrict__ deg, float* __restrict__ dinv) {
    int n = blockIdx.x * blockDim.x + threadIdx.x;
    if (n >= N_NODES) return;
    dinv[n] = rsqrtf((float)deg[n] + 1.0f);
}

// ---------------- hierarchical scan (deg -> row_start) ----------------
__global__ void k_scan1(const int* __restrict__ deg, int* __restrict__ bsum) {
    int t = threadIdx.x;
    int i = blockIdx.x * SCAN_B + t;
    __shared__ int ls[SCAN_B];
    ls[t] = (i < N_NODES) ? deg[i] : 0;
    __syncthreads();
    for (int off = SCAN_B / 2; off > 0; off >>= 1) {
        if (t < off) ls[t] += ls[t + off];
        __syncthreads();
    }
    if (t == 0) bsum[blockIdx.x] = ls[0];
}

__global__ void k_scan2(const int* __restrict__ bsum, int* __restrict__ boff,
                        int* __restrict__ row_start_last) {
    __shared__ int ls[256];
    int t = threadIdx.x;
    ls[t] = (t < SCAN_G) ? bsum[t] : 0;
    __syncthreads();
    for (int off = 1; off < 256; off <<= 1) {
        int u = (t >= off) ? ls[t - off] : 0;
        __syncthreads();
        ls[t] += u;
        __syncthreads();
    }
    boff[t] = (t == 0) ? 0 : ls[t - 1];
    if (t == 255) *row_start_last = ls[255];
}

__global__ void k_scan3(const int* __restrict__ deg, const int* __restrict__ boff,
                        int* __restrict__ row_start) {
    int t = threadIdx.x;
    int i = blockIdx.x * SCAN_B + t;
    int v = (i < N_NODES) ? deg[i] : 0;
    __shared__ int ls[SCAN_B];
    ls[t] = v;
    __syncthreads();
    for (int off = 1; off < SCAN_B; off <<= 1) {
        int u = (t >= off) ? ls[t - off] : 0;
        __syncthreads();
        ls[t] += u;
        __syncthreads();
    }
    if (i < N_NODES) row_start[i] = boff[blockIdx.x] + ls[t] - v;
}

// ---------------- node embedding: hb = bf16(x @ W_embed + b) ----------------
__global__ void k_embed(const float* __restrict__ x, const float* __restrict__ W,
                        const float* __restrict__ b, unsigned* __restrict__ hb) {
    __shared__ float Ws[F_IN * HD];
    __shared__ float xs[4 * F_IN];
    int t = threadIdx.x;
    for (int i = t; i < F_IN * HD; i += 256) Ws[i] = W[i];
    if (t < 4 * F_IN) {
        int r = t >> 5, c = t & 31;
        int node = blockIdx.x * 4 + r;
        xs[t] = (node < N_NODES) ? x[node * F_IN + c] : 0.f;
    }
    __syncthreads();
    int r = t >> 6, j = t & 63;
    int node = blockIdx.x * 4 + r;
    float acc = b[j];
#pragma unroll
    for (int k = 0; k < F_IN; ++k)
        acc = fmaf(xs[r * F_IN + k], Ws[k * HD + j], acc);
    float other = __shfl_xor(acc, 1);
    if (node < N_NODES && (j & 1) == 0)
        hb[node * 32 + (j >> 1)] = pack2(acc, other);
}

// ---------------- MFMA GEMM: Cf8[n] = fp8((relu(a*hb[n]+c) @ W) * dinv[n]) ----------------
__global__ void __launch_bounds__(256)
k_gemm_mfma(const unsigned* __restrict__ Ab, const float* __restrict__ W,
            const float* __restrict__ coef, const float* __restrict__ dinv,
            unsigned* __restrict__ Cf8) {
    __shared__ short Wt[64 * 72];          // Wt[j*72+k], bf16, ~9 KB
    __shared__ float Cs[4][16 * 66];       // per-wave C stage, ~16.9 KB
    int t = threadIdx.x;

    for (int i = t; i < HD * HD; i += 256) {
        int k = i >> 6, j = i & 63;
        Wt[j * 72 + k] = (short)bf16r(W[i]);
    }
    __syncthreads();

    int wid = t >> 6, lane = t & 63;
    int rlane = lane & 15, kb = lane >> 4;
    int base = blockIdx.x * 64 + wid * 16;
    int arow = base + rlane;
    if (arow > N_NODES - 1) arow = N_NODES - 1;   // clamp reads; writes guarded
    bool has_coef = (coef != nullptr);

    short8v afrag[2];
#pragma unroll
    for (int h = 0; h < 2; ++h) {
        uint4 p = *reinterpret_cast<const uint4*>(Ab + arow * 32 + h * 16 + kb * 4);
        union { uint4 u; short8v s; } cv;
        if (has_coef) {
            int k0 = h * 32 + kb * 8;
            float v0 = unlo(p.x), v1 = unhi(p.x), v2 = unlo(p.y), v3 = unhi(p.y);
            float v4 = unlo(p.z), v5 = unhi(p.z), v6 = unlo(p.w), v7 = unhi(p.w);
            v0 = fmaxf(fmaf(coef[k0 + 0], v0, coef[64 + k0 + 0]), 0.f);
            v1 = fmaxf(fmaf(coef[k0 + 1], v1, coef[64 + k0 + 1]), 0.f);
            v2 = fmaxf(fmaf(coef[k0 + 2], v2, coef[64 + k0 + 2]), 0.f);
            v3 = fmaxf(fmaf(coef[k0 + 3], v3, coef[64 + k0 + 3]), 0.f);
            v4 = fmaxf(fmaf(coef[k0 + 4], v4, coef[64 + k0 + 4]), 0.f);
            v5 = fmaxf(fmaf(coef[k0 + 5], v5, coef[64 + k0 + 5]), 0.f);
            v6 = fmaxf(fmaf(coef[k0 + 6], v6, coef[64 + k0 + 6]), 0.f);
            v7 = fmaxf(fmaf(coef[k0 + 7], v7, coef[64 + k0 + 7]), 0.f);
            cv.u.x = pack2(v0, v1); cv.u.y = pack2(v2, v3);
            cv.u.z = pack2(v4, v5); cv.u.w = pack2(v6, v7);
        } else {
            cv.u = p;
        }
        afrag[h] = cv.s;
    }

    f32x4 acc[4];
#pragma unroll
    for (int nt = 0; nt < 4; ++nt) acc[nt] = (f32x4){0.f, 0.f, 0.f, 0.f};

#pragma unroll
    for (int nt = 0; nt < 4; ++nt) {
        int col = nt * 16 + rlane;
#pragma unroll
        for (int h = 0; h < 2; ++h) {
            short8v b = *reinterpret_cast<const short8v*>(&Wt[col * 72 + h * 32 + kb * 8]);
            acc[nt] = __builtin_amdgcn_mfma_f32_16x16x32_bf16(afrag[h], b, acc[nt], 0, 0, 0);
        }
    }

    float dv[4];
#pragma unroll
    for (int r = 0; r < 4; ++r) {
        int g = base + kb * 4 + r;
        dv[r] = dinv[g > N_NODES - 1 ? N_NODES - 1 : g];
    }
#pragma unroll
    for (int nt = 0; nt < 4; ++nt) {
        int col = nt * 16 + rlane;
#pragma unroll
        for (int r = 0; r < 4; ++r)
            Cs[wid][(kb * 4 + r) * 66 + col] = acc[nt][r] * dv[r];
    }
    __syncthreads();

#pragma unroll
    for (int u = 0; u < 4; ++u) {
        int o = u * 64 + lane;
        int row = o >> 4, q = o & 15;
        int node = blockIdx.x * 64 + wid * 16 + row;
        if (node < N_NODES) {
            const float* cp = &Cs[wid][row * 66 + q * 4];
            Cf8[node * 16 + q] = pack_fp8x4(cp[0], cp[1], cp[2], cp[3]);
        }
    }
}

// ---------------- CSR gather (fp8 messages) + fused BN stats, bf16 h out ----------------
__global__ void __launch_bounds__(256)
k_gather_stats(const unsigned* __restrict__ xwf8, const int* __restrict__ row_start,
               const int* __restrict__ csr_src, const float* __restrict__ dinv,
               const float* __restrict__ cb, uint2* __restrict__ hb2,
               float* __restrict__ stats_sh) {
    int t = threadIdx.x;
    int q = t & 15;
    int r = t >> 4;
    int n = blockIdx.x * 16 + r;
    bool valid = (n < N_NODES);
    int beg = 0, end = 0;
    if (valid) { beg = row_start[n]; end = row_start[n + 1]; }
    float4 a0 = {0.f, 0.f, 0.f, 0.f}, a1 = {0.f, 0.f, 0.f, 0.f};
    if (valid) {
        unsigned p = xwf8[n * 16 + q];
        f32x2 lo = __builtin_amdgcn_cvt_pk_f32_fp8((int)p, false);
        f32x2 hi = __builtin_amdgcn_cvt_pk_f32_fp8((int)p, true);
        a0.x = lo[0]; a0.y = lo[1]; a0.z = hi[0]; a0.w = hi[1];
    }
    int e = beg;
    for (; e + 1 < end; e += 2) {
        int s0 = csr_src[e], s1 = csr_src[e + 1];
        unsigned p0 = xwf8[s0 * 16 + q];
        unsigned p1 = xwf8[s1 * 16 + q];
        f32x2 l0 = __builtin_amdgcn_cvt_pk_f32_fp8((int)p0, false);
        f32x2 h0 = __builtin_amdgcn_cvt_pk_f32_fp8((int)p0, true);
        f32x2 l1 = __builtin_amdgcn_cvt_pk_f32_fp8((int)p1, false);
        f32x2 h1 = __builtin_amdgcn_cvt_pk_f32_fp8((int)p1, true);
        a0.x += l0[0]; a0.y += l0[1]; a0.z += h0[0]; a0.w += h0[1];
        a1.x += l1[0]; a1.y += l1[1]; a1.z += h1[0]; a1.w += h1[1];
    }
    if (e < end) {
        int s0 = csr_src[e];
        unsigned p0 = xwf8[s0 * 16 + q];
        f32x2 l0 = __builtin_amdgcn_cvt_pk_f32_fp8((int)p0, false);
        f32x2 h0 = __builtin_amdgcn_cvt_pk_f32_fp8((int)p0, true);
        a0.x += l0[0]; a0.y += l0[1]; a0.z += h0[0]; a0.w += h0[1];
    }
    float dn = valid ? dinv[n] : 0.f;
    float4 h;
    h.x = fmaf(a0.x + a1.x, dn, cb[q * 4 + 0]);
    h.y = fmaf(a0.y + a1.y, dn, cb[q * 4 + 1]);
    h.z = fmaf(a0.z + a1.z, dn, cb[q * 4 + 2]);
    h.w = fmaf(a0.w + a1.w, dn, cb[q * 4 + 3]);
    if (valid) {
        uint2 o;
        o.x = pack2(h.x, h.y);
        o.y = pack2(h.z, h.w);
        hb2[n * 16 + q] = o;
    }

    float4 hs = valid ? h : make_float4(0.f, 0.f, 0.f, 0.f);
    __shared__ float4 ls_s[256], ls_q[256];   // 8 KB
    ls_s[t] = hs;
    float4 hq; hq.x = hs.x * hs.x; hq.y = hs.y * hs.y; hq.z = hs.z * hs.z; hq.w = hs.w * hs.w;
    ls_q[t] = hq;
    __syncthreads();
    if (t < 16) {
        float4 ss = ls_s[t], qq = ls_q[t];
        for (int rr = 1; rr < 16; ++rr) {
            float4 u = ls_s[rr * 16 + t], v = ls_q[rr * 16 + t];
            ss.x += u.x; ss.y += u.y; ss.z += u.z; ss.w += u.w;
            qq.x += v.x; qq.y += v.y; qq.z += v.z; qq.w += v.w;
        }
        float* sh = stats_sh + (blockIdx.x & (NSHADOW - 1)) * 128;
        atomicAdd(&sh[4 * t + 0], ss.x);
        atomicAdd(&sh[4 * t + 1], ss.y);
        atomicAdd(&sh[4 * t + 2], ss.z);
        atomicAdd(&sh[4 * t + 3], ss.w);
        atomicAdd(&sh[64 + 4 * t + 0], qq.x);
        atomicAdd(&sh[64 + 4 * t + 1], qq.y);
        atomicAdd(&sh[64 + 4 * t + 2], qq.z);
        atomicAdd(&sh[64 + 4 * t + 3], qq.w);
    }
}

// ---------------- shadow stats -> affine coef (a, c): bn(v) = a*v + c ----------------
__global__ void k_bn_coef(const float* __restrict__ stats_sh, const float* __restrict__ gamma,
                          const float* __restrict__ beta, float* __restrict__ coef) {
    int j = threadIdx.x;   // 64
    float s = 0.f, s2 = 0.f;
    for (int c = 0; c < NSHADOW; ++c) {
        s  += stats_sh[c * 128 + j];
        s2 += stats_sh[c * 128 + 64 + j];
    }
    float mu  = s * (1.0f / N_NODES);
    float var = s2 * (1.0f / N_NODES) - mu * mu;
    float rs  = rsqrtf(var + EPS);
    float a   = gamma[j] * rs;
    coef[j]      = a;
    coef[64 + j] = fmaf(-a, mu, beta[j]);
}

// ---------------- mean pool with fused BN+ReLU (bf16 h in) ----------------
__global__ void k_pool(const unsigned* __restrict__ hb, const float* __restrict__ coef,
                       float* __restrict__ pooled) {
    int t = threadIdx.x;
    int j = t & 63, rg = t >> 6;
    float a = coef[j], c = coef[64 + j];
    float s = 0.f;
    for (int n = blockIdx.x * 4 + rg; n < N_NODES; n += gridDim.x * 4) {
        unsigned p = hb[n * 32 + (j >> 1)];
        float v = (j & 1) ? unhi(p) : unlo(p);
        s += fmaxf(fmaf(a, v, c), 0.f);
    }
    __shared__ float ls[256];
    ls[t] = s;
    __syncthreads();
    if (t < 64)
        atomicAdd(&pooled[j], ls[t] + ls[t + 64] + ls[t + 128] + ls[t + 192]);
}

// ---------------- output ----------------
__global__ void k_out(const float* __restrict__ pooled, const float* __restrict__ Wout,
                      const float* __restrict__ bout, float* __restrict__ out) {
    int o = threadIdx.x;
    float acc = bout[o];
#pragma unroll
    for (int k = 0; k < HD; ++k)
        acc = fmaf(pooled[k] * (1.0f / N_NODES), Wout[k * HD + o], acc);
    out[o] = acc;
}

extern "C" void kernel_launch(void* const* d_in, const int* in_sizes, int n_in,
                              void* d_out, int out_size, void* d_ws, size_t ws_size,
                              hipStream_t stream) {
    const float* x        = (const float*)d_in[0];
    const int*   ei       = (const int*)  d_in[1];
    const float* W_embed  = (const float*)d_in[2];
    const float* b_embed  = (const float*)d_in[3];
    const float* conv_W   = (const float*)d_in[4];
    const float* conv_b   = (const float*)d_in[5];
    const float* bn_gamma = (const float*)d_in[6];
    const float* bn_beta  = (const float*)d_in[7];
    const float* W_out    = (const float*)d_in[8];
    const float* b_out    = (const float*)d_in[9];
    float* out = (float*)d_out;

    float* ws = (float*)d_ws;
    int*   deg       = (int*)ws;                          // N
    float* dinv      = ws + N_NODES;                      // N
    int*   row_start = (int*)(ws + 2 * N_NODES);          // N+1 (pad 8)
    float* small     = ws + 3 * N_NODES + 8;
    int*   bsum      = (int*)small;                       // 256
    int*   boff      = (int*)(small + 256);               // 256
    float* stats_sh  = small + 512;                       // NSHADOW*128 = 8192
    float* pooled    = small + 8704;                      // 64
    float* coef      = small + 8768;                      // 4*128 = 512
    int*   flag      = (int*)(small + 9280);              // 1 (pad 64)
    int*   csr_src   = (int*)(small + 9344);              // E
    int*   hcnt      = (int*)(small + 9344 + N_EDGES);    // NP*NB1 = 49000
    int*   off_bp    = hcnt + NP * NB1;                   // 49000
    int*   ptotal    = off_bp + NP * NB1;                 // 256
    int*   pbase     = ptotal + 256;                      // 256
    // align part_buf (uint2) to 8B: current offset = 9344+E+98512 = even ✓
    uint2* part_buf  = (uint2*)(pbase + 256);             // E uint2 (12.8 MB)
    float* bufA      = (float*)(part_buf + N_EDGES);      // N*32 uints (bf16 h)
    float* bufB      = bufA + N_NODES * 32;               // N*16 uints (fp8 xw)

    k_detect<<<1, 64, 0, stream>>>(ei, flag);
    k_p1_hist<<<NB1, 256, 0, stream>>>(ei, flag, hcnt);
    k_p2scan<<<NP, 256, 0, stream>>>(hcnt, off_bp, ptotal);
    k_p3scan<<<1, 256, 0, stream>>>(ptotal, pbase);
    k_p2_scatter<<<NB1, 256, 0, stream>>>(ei, flag, off_bp, pbase, part_buf);
    k_p3a_deg<<<NP, 256, 0, stream>>>(part_buf, pbase, ptotal, deg);
    k_dinv<<<(N_NODES + 255) / 256, 256, 0, stream>>>(deg, dinv);
    k_scan1<<<SCAN_G, SCAN_B, 0, stream>>>(deg, bsum);
    k_scan2<<<1, 256, 0, stream>>>(bsum, boff, ((int*)(ws + 2 * N_NODES)) + N_NODES);
    k_scan3<<<SCAN_G, SCAN_B, 0, stream>>>(deg, boff, row_start);
    k_embed<<<(N_NODES + 3) / 4, 256, 0, stream>>>(x, W_embed, b_embed, (unsigned*)bufA);
    k_p3b_csr<<<NP, 256, 0, stream>>>(part_buf, pbase, ptotal, row_start, csr_src);

    for (int l = 0; l < 4; ++l) {
        k_gemm_mfma<<<(N_NODES + 63) / 64, 256, 0, stream>>>(
            (const unsigned*)bufA, conv_W + l * HD * HD,
            l ? coef + (l - 1) * 128 : nullptr, dinv, (unsigned*)bufB);
        hipMemsetAsync(stats_sh, 0, NSHADOW * 128 * sizeof(float), stream);
        k_gather_stats<<<(N_NODES + 15) / 16, 256, 0, stream>>>(
            (const unsigned*)bufB, row_start, csr_src, dinv, conv_b + l * HD,
            (uint2*)bufA, stats_sh);
        k_bn_coef<<<1, 64, 0, stream>>>(stats_sh, bn_gamma + l * HD, bn_beta + l * HD,
                                        coef + l * 128);
    }

    hipMemsetAsync(pooled, 0, 64 * sizeof(float), stream);
    k_pool<<<1024, 256, 0, stream>>>((const unsigned*)bufA, coef + 3 * 128, pooled);
    k_out<<<1, 64, 0, stream>>>(pooled, W_out, b_out, out);
}

// Round 17
// 348.173 us; speedup vs baseline: 3.6477x; 1.1118x over previous
//
#include <hip/hip_runtime.h>

#define N_NODES 100000
#define N_EDGES 1600000
#define F_IN    32
#define HD      64
#define EPS     1e-5f
#define SCAN_B  512
#define SCAN_G  ((N_NODES + SCAN_B - 1) / SCAN_B)   // 196
#define NSHADOW 64
#define NP      196      // partitions (512 nodes each)
#define PWS     9        // partition width shift
#define NB1     250      // blocks in pass1/2
#define EPB     6400     // edges per block (250*6400 = E exactly)

typedef __attribute__((ext_vector_type(8))) short short8v;
typedef __attribute__((ext_vector_type(4))) float f32x4;
typedef __attribute__((ext_vector_type(2))) float f32x2;

// bf16 round-to-nearest-even pack/unpack
__device__ __forceinline__ unsigned bf16r(float f) {
    unsigned u = __float_as_uint(f);
    return (u + 0x7fffu + ((u >> 16) & 1u)) >> 16;
}
__device__ __forceinline__ unsigned pack2(float lo, float hi) {
    return bf16r(lo) | (bf16r(hi) << 16);
}
__device__ __forceinline__ float unlo(unsigned u) { return __uint_as_float(u << 16); }
__device__ __forceinline__ float unhi(unsigned u) { return __uint_as_float(u & 0xffff0000u); }

// fp8 e4m3 (OCP) pack via gfx950 HW converts
__device__ __forceinline__ unsigned pack_fp8x4(float a, float b, float c, float d) {
    int v = __builtin_amdgcn_cvt_pk_fp8_f32(a, b, 0, false);
    v = __builtin_amdgcn_cvt_pk_fp8_f32(c, d, v, true);
    return (unsigned)v;
}

// ---------------- edge-index dtype probe ----------------
__global__ void k_detect(const int* __restrict__ ei, int* __restrict__ flag) {
    if (threadIdx.x == 0 && blockIdx.x == 0) {
        int all_zero = 1;
        for (int k = 0; k < 64; ++k)
            if (ei[2 * k + 1] != 0) { all_zero = 0; break; }
        *flag = all_zero;   // 1 -> int64 layout, 0 -> int32 layout
    }
}

__device__ __forceinline__ int load_src(const int* ei, int e, int is64) {
    return is64 ? ei[2 * e] : ei[e];
}
__device__ __forceinline__ int load_dst(const int* ei, int e, int is64) {
    return is64 ? ei[2 * (N_EDGES + e)] : ei[N_EDGES + e];
}

// ---------------- CSR build pass 1: per-(block,partition) histogram ----------------
__global__ void __launch_bounds__(256)
k_p1_hist(const int* __restrict__ ei, const int* __restrict__ flag, int* __restrict__ hcnt) {
    __shared__ int hist[NP];
    int t = threadIdx.x, b = blockIdx.x;
    if (t < NP) hist[t] = 0;
    __syncthreads();
    int is64 = *flag;
#pragma unroll 5
    for (int i = 0; i < 25; ++i) {
        int e = b * EPB + i * 256 + t;
        int d = load_dst(ei, e, is64);
        atomicAdd(&hist[d >> PWS], 1);
    }
    __syncthreads();
    if (t < NP) hcnt[t * NB1 + b] = hist[t];
}

// ---------------- pass 2 scan: per-partition exclusive scan over blocks ----------------
__global__ void k_p2scan(const int* __restrict__ hcnt, int* __restrict__ off_bp,
                         int* __restrict__ ptotal) {
    __shared__ int ls[256];
    int t = threadIdx.x, p = blockIdx.x;
    int v = (t < NB1) ? hcnt[p * NB1 + t] : 0;
    ls[t] = v;
    __syncthreads();
    for (int off = 1; off < 256; off <<= 1) {
        int u = (t >= off) ? ls[t - off] : 0;
        __syncthreads();
        ls[t] += u;
        __syncthreads();
    }
    if (t < NB1) off_bp[p * NB1 + t] = ls[t] - v;
    if (t == 255) ptotal[p] = ls[255];
}

// ---------------- scan partition totals -> pbase ----------------
__global__ void k_p3scan(const int* __restrict__ ptotal, int* __restrict__ pbase) {
    __shared__ int ls[256];
    int t = threadIdx.x;
    int v = (t < NP) ? ptotal[t] : 0;
    ls[t] = v;
    __syncthreads();
    for (int off = 1; off < 256; off <<= 1) {
        int u = (t >= off) ? ls[t - off] : 0;
        __syncthreads();
        ls[t] += u;
        __syncthreads();
    }
    if (t < NP) pbase[t] = ls[t] - v;
}

// ---------------- pass 2: scatter edge records into partition buffer ----------------
__global__ void __launch_bounds__(256)
k_p2_scatter(const int* __restrict__ ei, const int* __restrict__ flag,
             const int* __restrict__ off_bp, const int* __restrict__ pbase,
             uint2* __restrict__ part_buf) {
    __shared__ int cursor[NP];
    int t = threadIdx.x, b = blockIdx.x;
    if (t < NP) cursor[t] = pbase[t] + off_bp[t * NB1 + b];
    __syncthreads();
    int is64 = *flag;
#pragma unroll 5
    for (int i = 0; i < 25; ++i) {
        int e = b * EPB + i * 256 + t;
        int s = load_src(ei, e, is64);
        int d = load_dst(ei, e, is64);
        int slot = atomicAdd(&cursor[d >> PWS], 1);
        part_buf[slot] = make_uint2((unsigned)s, (unsigned)d);
    }
}

// ---------------- pass 3a: per-partition degree histogram (+ fused dinv) ----------------
__global__ void __launch_bounds__(256)
k_p3a_deg(const uint2* __restrict__ part_buf, const int* __restrict__ pbase,
          const int* __restrict__ ptotal, int* __restrict__ deg,
          float* __restrict__ dinv) {
    __shared__ int hist[512];
    int t = threadIdx.x, p = blockIdx.x;
    hist[t] = 0; hist[t + 256] = 0;
    __syncthreads();
    int beg = pbase[p], cnt = ptotal[p];
    for (int r = t; r < cnt; r += 256)
        atomicAdd(&hist[part_buf[beg + r].y & 511], 1);
    __syncthreads();
    int n0 = (p << PWS) + t;
    if (n0 < N_NODES) {
        deg[n0] = hist[t];
        dinv[n0] = rsqrtf((float)hist[t] + 1.0f);
    }
    if (n0 + 256 < N_NODES) {
        deg[n0 + 256] = hist[t + 256];
        dinv[n0 + 256] = rsqrtf((float)hist[t + 256] + 1.0f);
    }
}

// ---------------- pass 3b: place src into CSR via LDS cursors ----------------
__global__ void __launch_bounds__(256)
k_p3b_csr(const uint2* __restrict__ part_buf, const int* __restrict__ pbase,
          const int* __restrict__ ptotal, const int* __restrict__ row_start,
          int* __restrict__ csr_src) {
    __shared__ int cur[512];
    int t = threadIdx.x, p = blockIdx.x;
    int n0 = (p << PWS) + t;
    cur[t]       = (n0 < N_NODES)       ? row_start[n0]       : 0;
    cur[t + 256] = (n0 + 256 < N_NODES) ? row_start[n0 + 256] : 0;
    __syncthreads();
    int beg = pbase[p], cnt = ptotal[p];
    for (int r = t; r < cnt; r += 256) {
        uint2 rec = part_buf[beg + r];
        int slot = atomicAdd(&cur[rec.y & 511], 1);
        csr_src[slot] = (int)rec.x;
    }
}

// ---------------- hierarchical scan (deg -> row_start) ----------------
__global__ void k_scan1(const int* __restrict__ deg, int* __restrict__ bsum) {
    int t = threadIdx.x;
    int i = blockIdx.x * SCAN_B + t;
    __shared__ int ls[SCAN_B];
    ls[t] = (i < N_NODES) ? deg[i] : 0;
    __syncthreads();
    for (int off = SCAN_B / 2; off > 0; off >>= 1) {
        if (t < off) ls[t] += ls[t + off];
        __syncthreads();
    }
    if (t == 0) bsum[blockIdx.x] = ls[0];
}

__global__ void k_scan2(const int* __restrict__ bsum, int* __restrict__ boff,
                        int* __restrict__ row_start_last) {
    __shared__ int ls[256];
    int t = threadIdx.x;
    ls[t] = (t < SCAN_G) ? bsum[t] : 0;
    __syncthreads();
    for (int off = 1; off < 256; off <<= 1) {
        int u = (t >= off) ? ls[t - off] : 0;
        __syncthreads();
        ls[t] += u;
        __syncthreads();
    }
    boff[t] = (t == 0) ? 0 : ls[t - 1];
    if (t == 255) *row_start_last = ls[255];
}

__global__ void k_scan3(const int* __restrict__ deg, const int* __restrict__ boff,
                        int* __restrict__ row_start) {
    int t = threadIdx.x;
    int i = blockIdx.x * SCAN_B + t;
    int v = (i < N_NODES) ? deg[i] : 0;
    __shared__ int ls[SCAN_B];
    ls[t] = v;
    __syncthreads();
    for (int off = 1; off < SCAN_B; off <<= 1) {
        int u = (t >= off) ? ls[t - off] : 0;
        __syncthreads();
        ls[t] += u;
        __syncthreads();
    }
    if (i < N_NODES) row_start[i] = boff[blockIdx.x] + ls[t] - v;
}

// ---------------- node embedding: hb = bf16(x @ W_embed + b) ----------------
__global__ void k_embed(const float* __restrict__ x, const float* __restrict__ W,
                        const float* __restrict__ b, unsigned* __restrict__ hb) {
    __shared__ float Ws[F_IN * HD];
    __shared__ float xs[4 * F_IN];
    int t = threadIdx.x;
    for (int i = t; i < F_IN * HD; i += 256) Ws[i] = W[i];
    if (t < 4 * F_IN) {
        int r = t >> 5, c = t & 31;
        int node = blockIdx.x * 4 + r;
        xs[t] = (node < N_NODES) ? x[node * F_IN + c] : 0.f;
    }
    __syncthreads();
    int r = t >> 6, j = t & 63;
    int node = blockIdx.x * 4 + r;
    float acc = b[j];
#pragma unroll
    for (int k = 0; k < F_IN; ++k)
        acc = fmaf(xs[r * F_IN + k], Ws[k * HD + j], acc);
    float other = __shfl_xor(acc, 1);
    if (node < N_NODES && (j & 1) == 0)
        hb[node * 32 + (j >> 1)] = pack2(acc, other);
}

// ---------------- MFMA GEMM: Cf8[n] = fp8((relu(a*hb[n]+c) @ W) * dinv[n]) ----------------
__global__ void __launch_bounds__(256)
k_gemm_mfma(const unsigned* __restrict__ Ab, const float* __restrict__ W,
            const float* __restrict__ coef, const float* __restrict__ dinv,
            unsigned* __restrict__ Cf8) {
    __shared__ short Wt[64 * 72];          // Wt[j*72+k], bf16, ~9 KB
    __shared__ float Cs[4][16 * 66];       // per-wave C stage, ~16.9 KB
    int t = threadIdx.x;

    for (int i = t; i < HD * HD; i += 256) {
        int k = i >> 6, j = i & 63;
        Wt[j * 72 + k] = (short)bf16r(W[i]);
    }
    __syncthreads();

    int wid = t >> 6, lane = t & 63;
    int rlane = lane & 15, kb = lane >> 4;
    int base = blockIdx.x * 64 + wid * 16;
    int arow = base + rlane;
    if (arow > N_NODES - 1) arow = N_NODES - 1;   // clamp reads; writes guarded
    bool has_coef = (coef != nullptr);

    short8v afrag[2];
#pragma unroll
    for (int h = 0; h < 2; ++h) {
        uint4 p = *reinterpret_cast<const uint4*>(Ab + arow * 32 + h * 16 + kb * 4);
        union { uint4 u; short8v s; } cv;
        if (has_coef) {
            int k0 = h * 32 + kb * 8;
            float v0 = unlo(p.x), v1 = unhi(p.x), v2 = unlo(p.y), v3 = unhi(p.y);
            float v4 = unlo(p.z), v5 = unhi(p.z), v6 = unlo(p.w), v7 = unhi(p.w);
            v0 = fmaxf(fmaf(coef[k0 + 0], v0, coef[64 + k0 + 0]), 0.f);
            v1 = fmaxf(fmaf(coef[k0 + 1], v1, coef[64 + k0 + 1]), 0.f);
            v2 = fmaxf(fmaf(coef[k0 + 2], v2, coef[64 + k0 + 2]), 0.f);
            v3 = fmaxf(fmaf(coef[k0 + 3], v3, coef[64 + k0 + 3]), 0.f);
            v4 = fmaxf(fmaf(coef[k0 + 4], v4, coef[64 + k0 + 4]), 0.f);
            v5 = fmaxf(fmaf(coef[k0 + 5], v5, coef[64 + k0 + 5]), 0.f);
            v6 = fmaxf(fmaf(coef[k0 + 6], v6, coef[64 + k0 + 6]), 0.f);
            v7 = fmaxf(fmaf(coef[k0 + 7], v7, coef[64 + k0 + 7]), 0.f);
            cv.u.x = pack2(v0, v1); cv.u.y = pack2(v2, v3);
            cv.u.z = pack2(v4, v5); cv.u.w = pack2(v6, v7);
        } else {
            cv.u = p;
        }
        afrag[h] = cv.s;
    }

    f32x4 acc[4];
#pragma unroll
    for (int nt = 0; nt < 4; ++nt) acc[nt] = (f32x4){0.f, 0.f, 0.f, 0.f};

#pragma unroll
    for (int nt = 0; nt < 4; ++nt) {
        int col = nt * 16 + rlane;
#pragma unroll
        for (int h = 0; h < 2; ++h) {
            short8v b = *reinterpret_cast<const short8v*>(&Wt[col * 72 + h * 32 + kb * 8]);
            acc[nt] = __builtin_amdgcn_mfma_f32_16x16x32_bf16(afrag[h], b, acc[nt], 0, 0, 0);
        }
    }

    float dv[4];
#pragma unroll
    for (int r = 0; r < 4; ++r) {
        int g = base + kb * 4 + r;
        dv[r] = dinv[g > N_NODES - 1 ? N_NODES - 1 : g];
    }
#pragma unroll
    for (int nt = 0; nt < 4; ++nt) {
        int col = nt * 16 + rlane;
#pragma unroll
        for (int r = 0; r < 4; ++r)
            Cs[wid][(kb * 4 + r) * 66 + col] = acc[nt][r] * dv[r];
    }
    __syncthreads();

#pragma unroll
    for (int u = 0; u < 4; ++u) {
        int o = u * 64 + lane;
        int row = o >> 4, q = o & 15;
        int node = blockIdx.x * 64 + wid * 16 + row;
        if (node < N_NODES) {
            const float* cp = &Cs[wid][row * 66 + q * 4];
            Cf8[node * 16 + q] = pack_fp8x4(cp[0], cp[1], cp[2], cp[3]);
        }
    }
}

// ---------------- CSR gather (fp8 messages) + fused BN stats, bf16 h out ----------------
// 64 nodes/block; 16-thread group handles 4 nodes serially; 4-deep edge unroll.
__global__ void __launch_bounds__(256)
k_gather_stats(const unsigned* __restrict__ xwf8, const int* __restrict__ row_start,
               const int* __restrict__ csr_src, const float* __restrict__ dinv,
               const float* __restrict__ cb, uint2* __restrict__ hb2,
               float* __restrict__ stats_sh) {
    int t = threadIdx.x;
    int q = t & 15;
    int r = t >> 4;
    float cb0 = cb[q * 4 + 0], cb1 = cb[q * 4 + 1];
    float cb2 = cb[q * 4 + 2], cb3 = cb[q * 4 + 3];
    float4 st_s = {0.f, 0.f, 0.f, 0.f}, st_q = {0.f, 0.f, 0.f, 0.f};

#pragma unroll
    for (int i = 0; i < 4; ++i) {
        int n = blockIdx.x * 64 + r * 4 + i;
        bool valid = (n < N_NODES);
        int beg = 0, end = 0;
        if (valid) { beg = row_start[n]; end = row_start[n + 1]; }
        float4 a0 = {0.f,0.f,0.f,0.f}, a1 = {0.f,0.f,0.f,0.f};
        float4 a2 = {0.f,0.f,0.f,0.f}, a3 = {0.f,0.f,0.f,0.f};
        if (valid) {
            unsigned p = xwf8[n * 16 + q];
            f32x2 lo = __builtin_amdgcn_cvt_pk_f32_fp8((int)p, false);
            f32x2 hi = __builtin_amdgcn_cvt_pk_f32_fp8((int)p, true);
            a0.x = lo[0]; a0.y = lo[1]; a0.z = hi[0]; a0.w = hi[1];
        }
        int e = beg;
        for (; e + 3 < end; e += 4) {
            int s0 = csr_src[e],     s1 = csr_src[e + 1];
            int s2 = csr_src[e + 2], s3 = csr_src[e + 3];
            unsigned p0 = xwf8[s0 * 16 + q], p1 = xwf8[s1 * 16 + q];
            unsigned p2 = xwf8[s2 * 16 + q], p3 = xwf8[s3 * 16 + q];
            f32x2 l0 = __builtin_amdgcn_cvt_pk_f32_fp8((int)p0, false);
            f32x2 h0 = __builtin_amdgcn_cvt_pk_f32_fp8((int)p0, true);
            f32x2 l1 = __builtin_amdgcn_cvt_pk_f32_fp8((int)p1, false);
            f32x2 h1 = __builtin_amdgcn_cvt_pk_f32_fp8((int)p1, true);
            f32x2 l2 = __builtin_amdgcn_cvt_pk_f32_fp8((int)p2, false);
            f32x2 h2 = __builtin_amdgcn_cvt_pk_f32_fp8((int)p2, true);
            f32x2 l3 = __builtin_amdgcn_cvt_pk_f32_fp8((int)p3, false);
            f32x2 h3 = __builtin_amdgcn_cvt_pk_f32_fp8((int)p3, true);
            a0.x += l0[0]; a0.y += l0[1]; a0.z += h0[0]; a0.w += h0[1];
            a1.x += l1[0]; a1.y += l1[1]; a1.z += h1[0]; a1.w += h1[1];
            a2.x += l2[0]; a2.y += l2[1]; a2.z += h2[0]; a2.w += h2[1];
            a3.x += l3[0]; a3.y += l3[1]; a3.z += h3[0]; a3.w += h3[1];
        }
        for (; e < end; ++e) {
            int s0 = csr_src[e];
            unsigned p0 = xwf8[s0 * 16 + q];
            f32x2 l0 = __builtin_amdgcn_cvt_pk_f32_fp8((int)p0, false);
            f32x2 h0 = __builtin_amdgcn_cvt_pk_f32_fp8((int)p0, true);
            a0.x += l0[0]; a0.y += l0[1]; a0.z += h0[0]; a0.w += h0[1];
        }
        float dn = valid ? dinv[n] : 0.f;
        float4 h;
        h.x = fmaf(a0.x + a1.x + a2.x + a3.x, dn, cb0);
        h.y = fmaf(a0.y + a1.y + a2.y + a3.y, dn, cb1);
        h.z = fmaf(a0.z + a1.z + a2.z + a3.z, dn, cb2);
        h.w = fmaf(a0.w + a1.w + a2.w + a3.w, dn, cb3);
        if (valid) {
            uint2 o;
            o.x = pack2(h.x, h.y);
            o.y = pack2(h.z, h.w);
            hb2[n * 16 + q] = o;
            st_s.x += h.x; st_s.y += h.y; st_s.z += h.z; st_s.w += h.w;
            st_q.x = fmaf(h.x, h.x, st_q.x); st_q.y = fmaf(h.y, h.y, st_q.y);
            st_q.z = fmaf(h.z, h.z, st_q.z); st_q.w = fmaf(h.w, h.w, st_q.w);
        }
    }

    // block-level stats reduce (sum, sumsq per column) then NSHADOW atomics
    __shared__ float4 ls_s[256], ls_q[256];   // 8 KB
    ls_s[t] = st_s; ls_q[t] = st_q;
    __syncthreads();
    if (t < 16) {
        float4 ss = ls_s[t], qq = ls_q[t];
        for (int rr = 1; rr < 16; ++rr) {
            float4 u = ls_s[rr * 16 + t], v = ls_q[rr * 16 + t];
            ss.x += u.x; ss.y += u.y; ss.z += u.z; ss.w += u.w;
            qq.x += v.x; qq.y += v.y; qq.z += v.z; qq.w += v.w;
        }
        float* sh = stats_sh + (blockIdx.x & (NSHADOW - 1)) * 128;
        atomicAdd(&sh[4 * t + 0], ss.x);
        atomicAdd(&sh[4 * t + 1], ss.y);
        atomicAdd(&sh[4 * t + 2], ss.z);
        atomicAdd(&sh[4 * t + 3], ss.w);
        atomicAdd(&sh[64 + 4 * t + 0], qq.x);
        atomicAdd(&sh[64 + 4 * t + 1], qq.y);
        atomicAdd(&sh[64 + 4 * t + 2], qq.z);
        atomicAdd(&sh[64 + 4 * t + 3], qq.w);
    }
}

// ---------------- shadow stats -> affine coef (a, c): bn(v) = a*v + c ----------------
__global__ void k_bn_coef(const float* __restrict__ stats_sh, const float* __restrict__ gamma,
                          const float* __restrict__ beta, float* __restrict__ coef) {
    int j = threadIdx.x;   // 64
    float s = 0.f, s2 = 0.f;
    for (int c = 0; c < NSHADOW; ++c) {
        s  += stats_sh[c * 128 + j];
        s2 += stats_sh[c * 128 + 64 + j];
    }
    float mu  = s * (1.0f / N_NODES);
    float var = s2 * (1.0f / N_NODES) - mu * mu;
    float rs  = rsqrtf(var + EPS);
    float a   = gamma[j] * rs;
    coef[j]      = a;
    coef[64 + j] = fmaf(-a, mu, beta[j]);
}

// ---------------- mean pool with fused BN+ReLU (bf16 h in) ----------------
__global__ void k_pool(const unsigned* __restrict__ hb, const float* __restrict__ coef,
                       float* __restrict__ pooled) {
    int t = threadIdx.x;
    int j = t & 63, rg = t >> 6;
    float a = coef[j], c = coef[64 + j];
    float s = 0.f;
    for (int n = blockIdx.x * 4 + rg; n < N_NODES; n += gridDim.x * 4) {
        unsigned p = hb[n * 32 + (j >> 1)];
        float v = (j & 1) ? unhi(p) : unlo(p);
        s += fmaxf(fmaf(a, v, c), 0.f);
    }
    __shared__ float ls[256];
    ls[t] = s;
    __syncthreads();
    if (t < 64)
        atomicAdd(&pooled[j], ls[t] + ls[t + 64] + ls[t + 128] + ls[t + 192]);
}

// ---------------- output ----------------
__global__ void k_out(const float* __restrict__ pooled, const float* __restrict__ Wout,
                      const float* __restrict__ bout, float* __restrict__ out) {
    int o = threadIdx.x;
    float acc = bout[o];
#pragma unroll
    for (int k = 0; k < HD; ++k)
        acc = fmaf(pooled[k] * (1.0f / N_NODES), Wout[k * HD + o], acc);
    out[o] = acc;
}

extern "C" void kernel_launch(void* const* d_in, const int* in_sizes, int n_in,
                              void* d_out, int out_size, void* d_ws, size_t ws_size,
                              hipStream_t stream) {
    const float* x        = (const float*)d_in[0];
    const int*   ei       = (const int*)  d_in[1];
    const float* W_embed  = (const float*)d_in[2];
    const float* b_embed  = (const float*)d_in[3];
    const float* conv_W   = (const float*)d_in[4];
    const float* conv_b   = (const float*)d_in[5];
    const float* bn_gamma = (const float*)d_in[6];
    const float* bn_beta  = (const float*)d_in[7];
    const float* W_out    = (const float*)d_in[8];
    const float* b_out    = (const float*)d_in[9];
    float* out = (float*)d_out;

    float* ws = (float*)d_ws;
    int*   deg       = (int*)ws;                          // N
    float* dinv      = ws + N_NODES;                      // N
    int*   row_start = (int*)(ws + 2 * N_NODES);          // N+1 (pad 8)
    float* small     = ws + 3 * N_NODES + 8;
    int*   bsum      = (int*)small;                       // 256
    int*   boff      = (int*)(small + 256);               // 256
    float* stats_sh  = small + 512;                       // NSHADOW*128 = 8192
    float* pooled    = small + 8704;                      // 64
    float* coef      = small + 8768;                      // 4*128 = 512
    int*   flag      = (int*)(small + 9280);              // 1 (pad 64)
    int*   csr_src   = (int*)(small + 9344);              // E
    int*   hcnt      = (int*)(small + 9344 + N_EDGES);    // NP*NB1 = 49000
    int*   off_bp    = hcnt + NP * NB1;                   // 49000
    int*   ptotal    = off_bp + NP * NB1;                 // 256
    int*   pbase     = ptotal + 256;                      // 256
    uint2* part_buf  = (uint2*)(pbase + 256);             // E uint2 (12.8 MB)
    float* bufA      = (float*)(part_buf + N_EDGES);      // N*32 uints (bf16 h)
    float* bufB      = bufA + N_NODES * 32;               // N*16 uints (fp8 xw)

    k_detect<<<1, 64, 0, stream>>>(ei, flag);
    k_p1_hist<<<NB1, 256, 0, stream>>>(ei, flag, hcnt);
    k_p2scan<<<NP, 256, 0, stream>>>(hcnt, off_bp, ptotal);
    k_p3scan<<<1, 256, 0, stream>>>(ptotal, pbase);
    k_p2_scatter<<<NB1, 256, 0, stream>>>(ei, flag, off_bp, pbase, part_buf);
    k_p3a_deg<<<NP, 256, 0, stream>>>(part_buf, pbase, ptotal, deg, dinv);
    k_scan1<<<SCAN_G, SCAN_B, 0, stream>>>(deg, bsum);
    k_scan2<<<1, 256, 0, stream>>>(bsum, boff, ((int*)(ws + 2 * N_NODES)) + N_NODES);
    k_scan3<<<SCAN_G, SCAN_B, 0, stream>>>(deg, boff, row_start);
    k_embed<<<(N_NODES + 3) / 4, 256, 0, stream>>>(x, W_embed, b_embed, (unsigned*)bufA);
    k_p3b_csr<<<NP, 256, 0, stream>>>(part_buf, pbase, ptotal, row_start, csr_src);

    for (int l = 0; l < 4; ++l) {
        k_gemm_mfma<<<(N_NODES + 63) / 64, 256, 0, stream>>>(
            (const unsigned*)bufA, conv_W + l * HD * HD,
            l ? coef + (l - 1) * 128 : nullptr, dinv, (unsigned*)bufB);
        hipMemsetAsync(stats_sh, 0, NSHADOW * 128 * sizeof(float), stream);
        k_gather_stats<<<(N_NODES + 63) / 64, 256, 0, stream>>>(
            (const unsigned*)bufB, row_start, csr_src, dinv, conv_b + l * HD,
            (uint2*)bufA, stats_sh);
        k_bn_coef<<<1, 64, 0, stream>>>(stats_sh, bn_gamma + l * HD, bn_beta + l * HD,
                                        coef + l * 128);
    }

    hipMemsetAsync(pooled, 0, 64 * sizeof(float), stream);
    k_pool<<<1024, 256, 0, stream>>>((const unsigned*)bufA, coef + 3 * 128, pooled);
    k_out<<<1, 64, 0, stream>>>(pooled, W_out, b_out, out);
}